// Round 3
// baseline (618.176 us; speedup 1.0000x reference)
//
#include <hip/hip_runtime.h>
#include <cmath>

typedef short short8 __attribute__((ext_vector_type(8)));
typedef float floatx4 __attribute__((ext_vector_type(4)));

#define T_LEN 4096
#define HC 256
#define NPOS (32 * 4096)
#define OUT_ELEMS (32 * 4 * 4096)

__device__ __forceinline__ ushort f2bf(float f) {
    uint u = __float_as_uint(f);
    u += 0x7FFFu + ((u >> 16) & 1u);
    return (ushort)(u >> 16);
}
__device__ __forceinline__ float bf2f(ushort u) {
    return __uint_as_float(((uint)u) << 16);
}
__device__ __forceinline__ uint addbf2(uint a, uint b) {
    const float lo = bf2f((ushort)(a & 0xffffu)) + bf2f((ushort)(b & 0xffffu));
    const float hi = bf2f((ushort)(a >> 16)) + bf2f((ushort)(b >> 16));
    return (uint)f2bf(lo) | ((uint)f2bf(hi) << 16);
}
// add bf16-pair y to two already-bf16-rounded floats ha/hb, repack
__device__ __forceinline__ uint addbf2f(uint y, float ha, float hb) {
    const float lo = bf2f((ushort)(y & 0xffffu)) + ha;
    const float hi = bf2f((ushort)(y >> 16)) + hb;
    return (uint)f2bf(lo) | ((uint)f2bf(hi) << 16);
}
// fast tanh-form gelu: 8 instr, no branches; |err vs exact-erf gelu| <~1.5e-3
__device__ __forceinline__ float gelu_f(float x) {
    const float x2 = x * x;
    const float w = fmaf(0.044715f * x2, x, x);
    const float e = __builtin_amdgcn_exp2f(2.3022084f * w);
    const float r = __builtin_amdgcn_rcpf(1.f + e);
    return fmaf(-x, r, x);
}
__device__ __forceinline__ float softplus_f(float x) {
    return (x > 20.f) ? x : log1pf(expf(x));
}
__device__ __forceinline__ void unpack8(uint4 r, float m, float* o) {
    o[0] = bf2f((ushort)(r.x & 0xffffu)) * m;
    o[1] = bf2f((ushort)(r.x >> 16)) * m;
    o[2] = bf2f((ushort)(r.y & 0xffffu)) * m;
    o[3] = bf2f((ushort)(r.y >> 16)) * m;
    o[4] = bf2f((ushort)(r.z & 0xffffu)) * m;
    o[5] = bf2f((ushort)(r.z >> 16)) * m;
    o[6] = bf2f((ushort)(r.w & 0xffffu)) * m;
    o[7] = bf2f((ushort)(r.w >> 16)) * m;
}

// ---------------------------------------------------------------- prep ----
__global__ __launch_bounds__(256) void prep_kernel(
    const float* __restrict__ cw, const float* __restrict__ pw,
    const float* __restrict__ x, const float* __restrict__ mask,
    ushort* __restrict__ wbf, ushort* __restrict__ pwbf,
    float* __restrict__ out)
{
    int idx = blockIdx.x * 256 + threadIdx.x;
    if (idx < 262144) {
        wbf[idx] = f2bf(cw[idx]);
    } else if (idx < 262144 + 16384) {
        int j = idx - 262144;
        int row = j >> 8, c = j & 255;
        pwbf[j] = (row < 58) ? f2bf(pw[row * 256 + c]) : (ushort)0;
    } else if (idx < 262144 + 16384 + 262144) {
        int j = idx - 278528;
        int b = j >> 13;
        int r = j & 8191;
        int ch = r >> 12;
        int t = r & 4095;
        out[b * 16384 + ch * 4096 + t] =
            x[b * 16384 + ch * 4096 + t] * mask[b * 4096 + t];
    } else if (idx < 262144 + 16384 + 262144 + 32) {
        out[OUT_ELEMS + (idx - 540672)] = 0.f;
    }
}

// -------------------------------------------------------------- fused0 ----
// Layer 0 fully fused, residual recomputed in epilogue (no hg stream; R2).
// vs R2: phase-1 x-loads software-pipelined — center taps + masks prefetched
// upfront, halo taps rotated one mm-iteration ahead (branch-free clamped
// address + zero mask: tap*0 == zero-pad, bit-exact).
__global__ __launch_bounds__(256, 3) void fused0_kernel(
    const float* __restrict__ x,
    ushort* __restrict__ hout, const ushort* __restrict__ wbf,
    const float* __restrict__ pre_w, const float* __restrict__ pre_b,
    const float* __restrict__ sep_w, const float* __restrict__ sep_b,
    const float* __restrict__ conv1_b,
    const float* __restrict__ n1g, const float* __restrict__ n1b,
    const float* __restrict__ n2g, const float* __restrict__ n2b,
    const float* __restrict__ mask)
{
    __shared__ __align__(16) ushort ylds[64 * 264];
    __shared__ float ssum[64][2];
    __shared__ float ssq[64][2];

    const int tid = threadIdx.x;
    const int lane = tid & 63;
    const int wv = tid >> 6;
    const int P = blockIdx.x;
    const int L = (P & 7) * 256 + (P >> 3);
    const int b = L >> 6;
    const int t0 = (L & 63) << 6;
    const float* maskb = mask + b * T_LEN;
    const float* xb0 = x + b * 16384;
    const float* xb1 = x + b * 16384 + 4096;
    const size_t hbase = (size_t)b * T_LEN * HC;

    // ---- phase 1: h from x + dwconv(1) + LN(n1) + gelu -> ylds ----
    {
        const int half = lane >> 5;
        const int ln32 = lane & 31;
        const int c0 = ln32 * 8;
        float w0[8], w1[8];
        #pragma unroll
        for (int j = 0; j < 4; ++j) {
            float4 wv4 = *(const float4*)(pre_w + c0 * 2 + 4 * j);
            w0[2 * j] = wv4.x; w1[2 * j] = wv4.y;
            w0[2 * j + 1] = wv4.z; w1[2 * j + 1] = wv4.w;
        }
        float pbv[8];
        *(float4*)(pbv + 0) = *(const float4*)(pre_b + c0);
        *(float4*)(pbv + 4) = *(const float4*)(pre_b + c0 + 4);
        float sw[24];
        #pragma unroll
        for (int j = 0; j < 6; ++j)
            *(float4*)(sw + 4 * j) = *(const float4*)(sep_w + c0 * 3 + 4 * j);
        float sbv[8], g1v[8], b1v[8];
        *(float4*)(sbv + 0) = *(const float4*)(sep_b + c0);
        *(float4*)(sbv + 4) = *(const float4*)(sep_b + c0 + 4);
        *(float4*)(g1v + 0) = *(const float4*)(n1g + c0);
        *(float4*)(g1v + 4) = *(const float4*)(n1g + c0 + 4);
        *(float4*)(b1v + 0) = *(const float4*)(n1b + c0);
        *(float4*)(b1v + 4) = *(const float4*)(n1b + c0 + 4);

        // prefetch all 8 center taps + masks upfront
        float xav[8], xcv[8], mcv[8];
        #pragma unroll
        for (int mm = 0; mm < 8; ++mm) {
            const int t = t0 + wv * 16 + mm * 2 + half;
            xav[mm] = xb0[t];
            xcv[mm] = xb1[t];
            mcv[mm] = maskb[t];
        }
        // rotating halo prefetch (dil = 1)
        float xamr, xcmr, mmr, xapr, xcpr, mpr;
        {
            const int t = t0 + wv * 16 + half;
            int tm = t - 1, tp = t + 1;
            const bool bm = tm >= 0, bp = tp < T_LEN;
            tm = bm ? tm : 0; tp = bp ? tp : T_LEN - 1;
            xamr = xb0[tm]; xcmr = xb1[tm]; mmr = bm ? maskb[tm] : 0.f;
            xapr = xb0[tp]; xcpr = xb1[tp]; mpr = bp ? maskb[tp] : 0.f;
        }

        for (int mm = 0; mm < 8; ++mm) {
            const int rloc = wv * 16 + mm * 2 + half;
            const int t = t0 + rloc;
            const float xa = xav[mm], xc = xcv[mm], mc = mcv[mm];
            const float xam = xamr, xcm = xcmr, mmk = mmr;
            const float xap = xapr, xcp = xcpr, mpk = mpr;
            if (mm < 7) {
                const int tn = t + 2;
                int tm = tn - 1, tp = tn + 1;
                const bool bm = tm >= 0, bp = tp < T_LEN;
                const int tmc = bm ? tm : 0, tpc = bp ? tp : T_LEN - 1;
                xamr = xb0[tmc]; xcmr = xb1[tmc]; mmr = bm ? maskb[tmc] : 0.f;
                xapr = xb0[tpc]; xcpr = xb1[tpc]; mpr = bp ? maskb[tpc] : 0.f;
            }

            float v[8];
            float s = 0.f, q = 0.f;
            #pragma unroll
            for (int j = 0; j < 8; ++j) {
                const float hcj = fmaf(w0[j], xa, fmaf(w1[j], xc, pbv[j]));
                const float hmj = fmaf(w0[j], xam, fmaf(w1[j], xcm, pbv[j])) * mmk;
                const float hpj = fmaf(w0[j], xap, fmaf(w1[j], xcp, pbv[j])) * mpk;
                const float vv = sw[3 * j] * hmj + sw[3 * j + 1] * (hcj * mc)
                               + sw[3 * j + 2] * hpj + sbv[j];
                v[j] = vv;
                s += vv;
                q += vv * vv;
            }
            #pragma unroll
            for (int d = 16; d > 0; d >>= 1) {
                s += __shfl_xor(s, d, 64);
                q += __shfl_xor(q, d, 64);
            }
            const float mean = s * (1.f / 256.f);
            const float var = q * (1.f / 256.f) - mean * mean;
            const float rs = rsqrtf(var + 1e-5f);
            uint pk[4];
            #pragma unroll
            for (int j = 0; j < 4; ++j) {
                const float ya = gelu_f((v[2 * j] - mean) * rs * g1v[2 * j] + b1v[2 * j]);
                const float yb = gelu_f((v[2 * j + 1] - mean) * rs * g1v[2 * j + 1] + b1v[2 * j + 1]);
                pk[j] = (uint)f2bf(ya) | ((uint)f2bf(yb) << 16);
            }
            *(uint4*)(&ylds[rloc * 264 + c0]) = make_uint4(pk[0], pk[1], pk[2], pk[3]);
        }
    }
    __syncthreads();

    // ---- phase 2: pipelined MFMA, A from LDS (R14 fused, verbatim) ----
    const int lw = lane & 15;
    const int quad = lane >> 4;
    const int mh = wv >> 1;
    const int nh = wv & 1;
    floatx4 acc[2][8];
    #pragma unroll
    for (int m = 0; m < 2; ++m)
        #pragma unroll
        for (int n = 0; n < 8; ++n) acc[m][n] = (floatx4){0.f, 0.f, 0.f, 0.f};

    const ushort* wb = wbf + (nh * 128 + lw) * 256 + quad * 8;
    const ushort* la0 = &ylds[(mh * 32 + lw) * 264 + quad * 8];
    const ushort* la1 = &ylds[(mh * 32 + 16 + lw) * 264 + quad * 8];

    short8 a0c = *(const short8*)(la0);
    short8 a1c = *(const short8*)(la1);
    short8 bcur[8], bnx[8];
    #pragma unroll
    for (int n = 0; n < 8; ++n)
        bcur[n] = *(const short8*)(wb + n * 4096);

    short8 a0n, a1n;
    #pragma unroll
    for (int kt = 0; kt < 8; ++kt) {
        if (kt < 7) {
            a0n = *(const short8*)(la0 + (kt + 1) * 32);
            a1n = *(const short8*)(la1 + (kt + 1) * 32);
            #pragma unroll
            for (int n = 0; n < 8; ++n)
                bnx[n] = *(const short8*)(wb + n * 4096 + (kt + 1) * 32);
        }
        #pragma unroll
        for (int n = 0; n < 8; ++n) {
            acc[0][n] = __builtin_amdgcn_mfma_f32_16x16x32_bf16(a0c, bcur[n], acc[0][n], 0, 0, 0);
            acc[1][n] = __builtin_amdgcn_mfma_f32_16x16x32_bf16(a1c, bcur[n], acc[1][n], 0, 0, 0);
        }
        a0c = a0n;
        a1c = a1n;
        #pragma unroll
        for (int n = 0; n < 8; ++n) bcur[n] = bnx[n];
    }

    float sum[2][4] = {{0, 0, 0, 0}, {0, 0, 0, 0}};
    float sq[2][4] = {{0, 0, 0, 0}, {0, 0, 0, 0}};
    #pragma unroll
    for (int n = 0; n < 8; ++n) {
        const float cb = conv1_b[nh * 128 + n * 16 + lw];
        #pragma unroll
        for (int m = 0; m < 2; ++m)
            #pragma unroll
            for (int r = 0; r < 4; ++r) {
                const float val = acc[m][n][r] + cb;
                acc[m][n][r] = val;
                sum[m][r] += val;
                sq[m][r] += val * val;
            }
    }
    #pragma unroll
    for (int d = 1; d < 16; d <<= 1) {
        #pragma unroll
        for (int m = 0; m < 2; ++m)
            #pragma unroll
            for (int r = 0; r < 4; ++r) {
                sum[m][r] += __shfl_xor(sum[m][r], d, 64);
                sq[m][r] += __shfl_xor(sq[m][r], d, 64);
            }
    }
    if (lw == 0) {
        #pragma unroll
        for (int m = 0; m < 2; ++m)
            #pragma unroll
            for (int r = 0; r < 4; ++r) {
                ssum[mh * 32 + m * 16 + quad * 4 + r][nh] = sum[m][r];
                ssq[mh * 32 + m * 16 + quad * 4 + r][nh] = sq[m][r];
            }
    }
    __syncthreads();

    float mean[2][4], rsv[2][4];
    #pragma unroll
    for (int m = 0; m < 2; ++m)
        #pragma unroll
        for (int r = 0; r < 4; ++r) {
            const int row = mh * 32 + m * 16 + quad * 4 + r;
            const float s = ssum[row][0] + ssum[row][1];
            const float q = ssq[row][0] + ssq[row][1];
            mean[m][r] = s * (1.f / 256.f);
            const float var = q * (1.f / 256.f) - mean[m][r] * mean[m][r];
            rsv[m][r] = rsqrtf(var + 1e-5f);
        }
    #pragma unroll
    for (int n = 0; n < 8; ++n) {
        const int o = nh * 128 + n * 16 + lw;
        const float g2 = n2g[o], b2 = n2b[o];
        #pragma unroll
        for (int m = 0; m < 2; ++m)
            #pragma unroll
            for (int r = 0; r < 4; ++r) {
                const int row = mh * 32 + m * 16 + quad * 4 + r;
                const float y = gelu_f((acc[m][n][r] - mean[m][r]) * rsv[m][r] * g2 + b2);
                ylds[row * 264 + o] = f2bf(y);
            }
    }
    __syncthreads();

    // ---- epilogue: recompute residual h from x (bf16-rounded), add y ----
    {
        const int half = lane >> 5;
        const int ln32 = lane & 31;
        const int c0 = ln32 * 8;
        float w0[8], w1[8], pbv[8];
        #pragma unroll
        for (int j = 0; j < 4; ++j) {
            float4 wv4 = *(const float4*)(pre_w + c0 * 2 + 4 * j);
            w0[2 * j] = wv4.x; w1[2 * j] = wv4.y;
            w0[2 * j + 1] = wv4.z; w1[2 * j + 1] = wv4.w;
        }
        *(float4*)(pbv + 0) = *(const float4*)(pre_b + c0);
        *(float4*)(pbv + 4) = *(const float4*)(pre_b + c0 + 4);
        #pragma unroll
        for (int mm = 0; mm < 8; ++mm) {
            const int rloc = wv * 16 + mm * 2 + half;
            const int t = t0 + rloc;
            const float xa = xb0[t], xc = xb1[t];
            const uint4 yv = *(const uint4*)(&ylds[rloc * 264 + c0]);
            uint ov[4];
            const uint yw[4] = {yv.x, yv.y, yv.z, yv.w};
            #pragma unroll
            for (int j = 0; j < 4; ++j) {
                const float ha = bf2f(f2bf(fmaf(w0[2 * j], xa, fmaf(w1[2 * j], xc, pbv[2 * j]))));
                const float hb = bf2f(f2bf(fmaf(w0[2 * j + 1], xa, fmaf(w1[2 * j + 1], xc, pbv[2 * j + 1]))));
                ov[j] = addbf2f(yw[j], ha, hb);
            }
            *(uint4*)(hout + hbase + (size_t)t * HC + c0) =
                make_uint4(ov[0], ov[1], ov[2], ov[3]);
        }
    }
}

// --------------------------------------------------------------- fused ----
// Layers 1-3. vs R2: (a) halo taps rotated one mm-iteration ahead,
// branch-free (clamped address + zero mask — h buffer fully initialized so
// clamped loads are safe; tap*0 == zero-pad, bit-exact); (b) hv residual
// loads hoisted ABOVE the MFMA kt-loop so their latency hides under MFMA.
__global__ __launch_bounds__(256, 3) void fused_kernel(
    const ushort* __restrict__ hin, ushort* __restrict__ hout,
    const ushort* __restrict__ wbf,
    const float* __restrict__ sep_w, const float* __restrict__ sep_b,
    const float* __restrict__ conv1_b,
    const float* __restrict__ n1g, const float* __restrict__ n1b,
    const float* __restrict__ n2g, const float* __restrict__ n2b,
    const float* __restrict__ mask, int dil)
{
    __shared__ __align__(16) ushort ylds[64 * 264];
    __shared__ float ssum[64][2];
    __shared__ float ssq[64][2];

    const int tid = threadIdx.x;
    const int lane = tid & 63;
    const int wv = tid >> 6;
    const int P = blockIdx.x;
    const int L = (P & 7) * 256 + (P >> 3);
    const int b = L >> 6;
    const int t0 = (L & 63) << 6;
    const float* maskb = mask + b * T_LEN;
    const size_t hbase = (size_t)b * T_LEN * HC;

    {
        const int half = lane >> 5;
        const int ln32 = lane & 31;
        const int c0 = ln32 * 8;
        float sw[24];
        #pragma unroll
        for (int j = 0; j < 6; ++j)
            *(float4*)(sw + 4 * j) = *(const float4*)(sep_w + c0 * 3 + 4 * j);
        float sbv[8], g1v[8], b1v[8];
        *(float4*)(sbv + 0) = *(const float4*)(sep_b + c0);
        *(float4*)(sbv + 4) = *(const float4*)(sep_b + c0 + 4);
        *(float4*)(g1v + 0) = *(const float4*)(n1g + c0);
        *(float4*)(g1v + 4) = *(const float4*)(n1g + c0 + 4);
        *(float4*)(b1v + 0) = *(const float4*)(n1b + c0);
        *(float4*)(b1v + 4) = *(const float4*)(n1b + c0 + 4);

        // prefetch all 8 center taps + masks upfront
        uint4 hraw[8];
        float mcv[8];
        #pragma unroll
        for (int mm = 0; mm < 8; ++mm) {
            const int t = t0 + wv * 16 + mm * 2 + half;
            hraw[mm] = *(const uint4*)(hin + hbase + (size_t)t * HC + c0);
            mcv[mm] = maskb[t];
        }
        // rotating halo prefetch
        uint4 hmr, hpr;
        float mmr, mpr;
        {
            const int t = t0 + wv * 16 + half;
            int tm = t - dil, tp = t + dil;
            const bool bm = tm >= 0, bp = tp < T_LEN;
            const int tmc = bm ? tm : 0, tpc = bp ? tp : T_LEN - 1;
            hmr = *(const uint4*)(hin + hbase + (size_t)tmc * HC + c0);
            hpr = *(const uint4*)(hin + hbase + (size_t)tpc * HC + c0);
            mmr = bm ? maskb[tmc] : 0.f;
            mpr = bp ? maskb[tpc] : 0.f;
        }

        for (int mm = 0; mm < 8; ++mm) {
            const int rloc = wv * 16 + mm * 2 + half;
            const int t = t0 + rloc;
            const uint4 hmc = hmr, hpc = hpr;
            const float mmc = mmr, mpc = mpr;
            if (mm < 7) {
                const int tn = t + 2;
                int tm = tn - dil, tp = tn + dil;
                const bool bm = tm >= 0, bp = tp < T_LEN;
                const int tmc = bm ? tm : 0, tpc = bp ? tp : T_LEN - 1;
                hmr = *(const uint4*)(hin + hbase + (size_t)tmc * HC + c0);
                hpr = *(const uint4*)(hin + hbase + (size_t)tpc * HC + c0);
                mmr = bm ? maskb[tmc] : 0.f;
                mpr = bp ? maskb[tpc] : 0.f;
            }
            float hm[8], hp[8], hc[8];
            unpack8(hmc, mmc, hm);
            unpack8(hpc, mpc, hp);
            unpack8(hraw[mm], mcv[mm], hc);
            float v[8];
            float s = 0.f, q = 0.f;
            #pragma unroll
            for (int j = 0; j < 8; ++j) {
                const float vv = sw[3 * j] * hm[j] + sw[3 * j + 1] * hc[j]
                               + sw[3 * j + 2] * hp[j] + sbv[j];
                v[j] = vv;
                s += vv;
                q += vv * vv;
            }
            #pragma unroll
            for (int d = 16; d > 0; d >>= 1) {
                s += __shfl_xor(s, d, 64);
                q += __shfl_xor(q, d, 64);
            }
            const float mean = s * (1.f / 256.f);
            const float var = q * (1.f / 256.f) - mean * mean;
            const float rs = rsqrtf(var + 1e-5f);
            uint pk[4];
            #pragma unroll
            for (int j = 0; j < 4; ++j) {
                const float ya = gelu_f((v[2 * j] - mean) * rs * g1v[2 * j] + b1v[2 * j]);
                const float yb = gelu_f((v[2 * j + 1] - mean) * rs * g1v[2 * j + 1] + b1v[2 * j + 1]);
                pk[j] = (uint)f2bf(ya) | ((uint)f2bf(yb) << 16);
            }
            *(uint4*)(&ylds[rloc * 264 + c0]) = make_uint4(pk[0], pk[1], pk[2], pk[3]);
        }
    }
    __syncthreads();

    const int lw = lane & 15;
    const int quad = lane >> 4;
    const int mh = wv >> 1;
    const int nh = wv & 1;
    floatx4 acc[2][8];
    #pragma unroll
    for (int m = 0; m < 2; ++m)
        #pragma unroll
        for (int n = 0; n < 8; ++n) acc[m][n] = (floatx4){0.f, 0.f, 0.f, 0.f};

    // hv residual loads issued BEFORE the MFMA loop — latency hides under MFMA
    uint4 hv[8];
    #pragma unroll
    for (int jj = 0; jj < 8; ++jj) {
        const int idx = jj * 256 + tid;
        const int row = idx >> 5, seg = idx & 31;
        hv[jj] = *(const uint4*)(hin + hbase + (size_t)(t0 + row) * HC + seg * 8);
    }

    const ushort* wb = wbf + (nh * 128 + lw) * 256 + quad * 8;
    const ushort* la0 = &ylds[(mh * 32 + lw) * 264 + quad * 8];
    const ushort* la1 = &ylds[(mh * 32 + 16 + lw) * 264 + quad * 8];

    short8 a0c = *(const short8*)(la0);
    short8 a1c = *(const short8*)(la1);
    short8 bcur[8], bnx[8];
    #pragma unroll
    for (int n = 0; n < 8; ++n)
        bcur[n] = *(const short8*)(wb + n * 4096);

    short8 a0n, a1n;
    #pragma unroll
    for (int kt = 0; kt < 8; ++kt) {
        if (kt < 7) {
            a0n = *(const short8*)(la0 + (kt + 1) * 32);
            a1n = *(const short8*)(la1 + (kt + 1) * 32);
            #pragma unroll
            for (int n = 0; n < 8; ++n)
                bnx[n] = *(const short8*)(wb + n * 4096 + (kt + 1) * 32);
        }
        #pragma unroll
        for (int n = 0; n < 8; ++n) {
            acc[0][n] = __builtin_amdgcn_mfma_f32_16x16x32_bf16(a0c, bcur[n], acc[0][n], 0, 0, 0);
            acc[1][n] = __builtin_amdgcn_mfma_f32_16x16x32_bf16(a1c, bcur[n], acc[1][n], 0, 0, 0);
        }
        a0c = a0n;
        a1c = a1n;
        #pragma unroll
        for (int n = 0; n < 8; ++n) bcur[n] = bnx[n];
    }

    float sum[2][4] = {{0, 0, 0, 0}, {0, 0, 0, 0}};
    float sq[2][4] = {{0, 0, 0, 0}, {0, 0, 0, 0}};
    #pragma unroll
    for (int n = 0; n < 8; ++n) {
        const float cb = conv1_b[nh * 128 + n * 16 + lw];
        #pragma unroll
        for (int m = 0; m < 2; ++m)
            #pragma unroll
            for (int r = 0; r < 4; ++r) {
                const float val = acc[m][n][r] + cb;
                acc[m][n][r] = val;
                sum[m][r] += val;
                sq[m][r] += val * val;
            }
    }
    #pragma unroll
    for (int d = 1; d < 16; d <<= 1) {
        #pragma unroll
        for (int m = 0; m < 2; ++m)
            #pragma unroll
            for (int r = 0; r < 4; ++r) {
                sum[m][r] += __shfl_xor(sum[m][r], d, 64);
                sq[m][r] += __shfl_xor(sq[m][r], d, 64);
            }
    }
    if (lw == 0) {
        #pragma unroll
        for (int m = 0; m < 2; ++m)
            #pragma unroll
            for (int r = 0; r < 4; ++r) {
                ssum[mh * 32 + m * 16 + quad * 4 + r][nh] = sum[m][r];
                ssq[mh * 32 + m * 16 + quad * 4 + r][nh] = sq[m][r];
            }
    }
    __syncthreads();

    float mean[2][4], rsv[2][4];
    #pragma unroll
    for (int m = 0; m < 2; ++m)
        #pragma unroll
        for (int r = 0; r < 4; ++r) {
            const int row = mh * 32 + m * 16 + quad * 4 + r;
            const float s = ssum[row][0] + ssum[row][1];
            const float q = ssq[row][0] + ssq[row][1];
            mean[m][r] = s * (1.f / 256.f);
            const float var = q * (1.f / 256.f) - mean[m][r] * mean[m][r];
            rsv[m][r] = rsqrtf(var + 1e-5f);
        }
    #pragma unroll
    for (int n = 0; n < 8; ++n) {
        const int o = nh * 128 + n * 16 + lw;
        const float g2 = n2g[o], b2 = n2b[o];
        #pragma unroll
        for (int m = 0; m < 2; ++m)
            #pragma unroll
            for (int r = 0; r < 4; ++r) {
                const int row = mh * 32 + m * 16 + quad * 4 + r;
                const float y = gelu_f((acc[m][n][r] - mean[m][r]) * rsv[m][r] * g2 + b2);
                ylds[row * 264 + o] = f2bf(y);
            }
    }
    __syncthreads();

    #pragma unroll
    for (int jj = 0; jj < 8; ++jj) {
        const int idx = jj * 256 + tid;
        const int row = idx >> 5, seg = idx & 31;
        const size_t g = hbase + (size_t)(t0 + row) * HC + seg * 8;
        const uint4 yv = *(const uint4*)(&ylds[row * 264 + seg * 8]);
        uint4 ov;
        ov.x = addbf2(yv.x, hv[jj].x);
        ov.y = addbf2(yv.y, hv[jj].y);
        ov.z = addbf2(yv.z, hv[jj].z);
        ov.w = addbf2(yv.w, hv[jj].w);
        *(uint4*)(hout + g) = ov;
    }
}

// ---------------------------------------------------------- proj+spline ----
// LDS union: slds (16.6KB) aliases alds (33.8KB) — all alds reads complete
// before the extra __syncthreads(), so reuse is safe. Streaming kernel
// (no later re-read of its input), so 4 blocks/CU is L2-safe here.
__global__ __launch_bounds__(256, 4) void proj_kernel(
    const ushort* __restrict__ hin, const ushort* __restrict__ pwbf,
    const float* __restrict__ projb, const float* __restrict__ x,
    const float* __restrict__ mask, float* __restrict__ out)
{
    __shared__ __align__(16) ushort alds[64 * 264];
    __shared__ float red[4];
    float* slds = reinterpret_cast<float*>(alds);   // stride 65 floats

    const int tid = threadIdx.x;
    const int lane = tid & 63;
    const int wv = tid >> 6;
    const int blk = blockIdx.x;
    const int b = blk >> 6;
    const int t0 = (blk & 63) << 6;
    const size_t hbase = (size_t)b * T_LEN * HC;

    #pragma unroll
    for (int jj = 0; jj < 8; ++jj) {
        const int idx = jj * 256 + tid;
        const int row = idx >> 5, seg = idx & 31;
        short8 v = *(const short8*)(hin + hbase + (size_t)(t0 + row) * HC + seg * 8);
        *(short8*)(&alds[row * 264 + seg * 8]) = v;
    }
    __syncthreads();

    const int lw = lane & 15;
    const int quad = lane >> 4;
    floatx4 acc[4];
    #pragma unroll
    for (int n = 0; n < 4; ++n) acc[n] = (floatx4){0.f, 0.f, 0.f, 0.f};
    #pragma unroll
    for (int kt = 0; kt < 8; ++kt) {
        short8 a = *(short8*)(&alds[(wv * 16 + lw) * 264 + kt * 32 + quad * 8]);
        #pragma unroll
        for (int n = 0; n < 4; ++n) {
            short8 bb = *(const short8*)(pwbf + (n * 16 + lw) * 256 + kt * 32 + quad * 8);
            acc[n] = __builtin_amdgcn_mfma_f32_16x16x32_bf16(a, bb, acc[n], 0, 0, 0);
        }
    }
    __syncthreads();   // all alds reads done -> safe to reuse as slds
    #pragma unroll
    for (int n = 0; n < 4; ++n) {
        const int o = n * 16 + lw;
        const float pb = (o < 58) ? projb[o] : 0.f;
        #pragma unroll
        for (int r = 0; r < 4; ++r) {
            const int row = wv * 16 + quad * 4 + r;
            const float mv = mask[b * T_LEN + t0 + row];
            slds[row * 65 + o] = acc[n][r] * mv + pb;
        }
    }
    __syncthreads();

    float contrib = 0.f;
    if (tid < 128) {
        const int pos = tid >> 1;
        const int ch = tid & 1;
        const int t = t0 + pos;
        float sv[29];
        #pragma unroll
        for (int j = 0; j < 29; ++j) sv[j] = slds[pos * 65 + ch * 29 + j];
        const float x1 = x[b * 16384 + (2 + ch) * 4096 + t];

        const float SC = 0.0625f;
        float cwv[11], wdv[10], chv[11], htv[10], dvv[11];
        {
            float u[10];
            float mx = -1e30f;
            #pragma unroll
            for (int j = 0; j < 10; ++j) { u[j] = sv[j] * SC; mx = fmaxf(mx, u[j]); }
            float ssm = 0.f;
            #pragma unroll
            for (int j = 0; j < 10; ++j) { u[j] = expf(u[j] - mx); ssm += u[j]; }
            const float inv = 1.f / ssm;
            float cum = 0.f;
            cwv[0] = -5.f;
            #pragma unroll
            for (int j = 0; j < 10; ++j) {
                cum += 0.001f + 0.99f * u[j] * inv;
                cwv[j + 1] = 10.f * cum - 5.f;
            }
            cwv[10] = 5.f;
            #pragma unroll
            for (int j = 0; j < 10; ++j) wdv[j] = cwv[j + 1] - cwv[j];
        }
        {
            float u[10];
            float mx = -1e30f;
            #pragma unroll
            for (int j = 0; j < 10; ++j) { u[j] = sv[10 + j] * SC; mx = fmaxf(mx, u[j]); }
            float ssm = 0.f;
            #pragma unroll
            for (int j = 0; j < 10; ++j) { u[j] = expf(u[j] - mx); ssm += u[j]; }
            const float inv = 1.f / ssm;
            float cum = 0.f;
            chv[0] = -5.f;
            #pragma unroll
            for (int j = 0; j < 10; ++j) {
                cum += 0.001f + 0.99f * u[j] * inv;
                chv[j + 1] = 10.f * cum - 5.f;
            }
            chv[10] = 5.f;
            #pragma unroll
            for (int j = 0; j < 10; ++j) htv[j] = chv[j + 1] - chv[j];
        }
        dvv[0] = 1.f;
        dvv[10] = 1.f;
        #pragma unroll
        for (int j = 1; j <= 9; ++j) dvv[j] = 0.001f + softplus_f(sv[19 + j]);

        const bool inside = (x1 >= -5.f) && (x1 <= 5.f);
        const float xc = fminf(fmaxf(x1, -5.f), 5.f);
        float in_cw = cwv[0], in_w = wdv[0], in_ch = chv[0], in_h = htv[0];
        float dk = dvv[0], dk1 = dvv[1];
        #pragma unroll
        for (int j = 1; j < 10; ++j) {
            const bool ge = (xc >= cwv[j]);
            in_cw = ge ? cwv[j] : in_cw;
            in_w  = ge ? wdv[j] : in_w;
            in_ch = ge ? chv[j] : in_ch;
            in_h  = ge ? htv[j] : in_h;
            dk    = ge ? dvv[j] : dk;
            dk1   = ge ? dvv[j + 1] : dk1;
        }
        const float th = (xc - in_cw) / in_w;
        const float t1m = th * (1.f - th);
        const float dl = in_h / in_w;
        const float num = in_h * (dl * th * th + dk * t1m);
        const float den = dl + (dk + dk1 - 2.f * dl) * t1m;
        float yv = in_ch + num / den;
        const float omt = 1.f - th;
        const float dnum = dl * dl * (dk1 * th * th + 2.f * dl * t1m + dk * omt * omt);
        float lad = logf(dnum) - 2.f * logf(den);
        if (!inside) { yv = x1; lad = 0.f; }
        const float mv = mask[b * T_LEN + t];
        out[b * 16384 + (2 + ch) * 4096 + t] = yv * mv;
        contrib = lad * mv;
    }
    #pragma unroll
    for (int d = 32; d > 0; d >>= 1) contrib += __shfl_xor(contrib, d, 64);
    if (lane == 0) red[wv] = contrib;
    __syncthreads();
    if (tid == 0) atomicAdd(out + OUT_ELEMS + b, red[0] + red[1] + red[2] + red[3]);
}

// -------------------------------------------------------------- launch ----
extern "C" void kernel_launch(void* const* d_in, const int* in_sizes, int n_in,
                              void* d_out, int out_size, void* d_ws, size_t ws_size,
                              hipStream_t stream) {
    const float* x      = (const float*)d_in[0];
    const float* mask   = (const float*)d_in[1];
    const float* pre_w  = (const float*)d_in[2];
    const float* pre_b  = (const float*)d_in[3];
    const float* sep_w  = (const float*)d_in[4];
    const float* sep_b  = (const float*)d_in[5];
    const float* conv1w = (const float*)d_in[6];
    const float* conv1b = (const float*)d_in[7];
    const float* n1g    = (const float*)d_in[8];
    const float* n1b    = (const float*)d_in[9];
    const float* n2g    = (const float*)d_in[10];
    const float* n2b    = (const float*)d_in[11];
    const float* projw  = (const float*)d_in[12];
    const float* projb  = (const float*)d_in[13];
    float* out = (float*)d_out;

    ushort* h0   = (ushort*)d_ws;
    ushort* h1   = h0 + (size_t)NPOS * HC;
    ushort* wbf  = h1 + (size_t)NPOS * HC;
    ushort* pwbf = wbf + 4 * 256 * 256;

    prep_kernel<<<2113, 256, 0, stream>>>(conv1w, projw, x, mask, wbf, pwbf, out);

    // layer 0: fully fused, residual recomputed in epilogue (no hg stream)
    fused0_kernel<<<2048, 256, 0, stream>>>(x, h1, wbf,
        pre_w, pre_b, sep_w, sep_b, conv1b, n1g, n1b, n2g, n2b, mask);

    // layers 1-3: fully fused (y stays in LDS); ping-pong, never in-place
    fused_kernel<<<2048, 256, 0, stream>>>(h1, h0, wbf + 1 * 65536,
        sep_w + 1 * 768, sep_b + 1 * 256, conv1b + 1 * 256,
        n1g + 1 * 256, n1b + 1 * 256, n2g + 1 * 256, n2b + 1 * 256, mask, 3);
    fused_kernel<<<2048, 256, 0, stream>>>(h0, h1, wbf + 2 * 65536,
        sep_w + 2 * 768, sep_b + 2 * 256, conv1b + 2 * 256,
        n1g + 2 * 256, n1b + 2 * 256, n2g + 2 * 256, n2b + 2 * 256, mask, 9);
    fused_kernel<<<2048, 256, 0, stream>>>(h1, h0, wbf + 3 * 65536,
        sep_w + 3 * 768, sep_b + 3 * 256, conv1b + 3 * 256,
        n1g + 3 * 256, n1b + 3 * 256, n2g + 3 * 256, n2b + 3 * 256, mask, 27);

    proj_kernel<<<2048, 256, 0, stream>>>(h0, pwbf, projb, x, mask, out);
}

// Round 4
// 547.237 us; speedup vs baseline: 1.1296x; 1.1296x over previous
//
#include <hip/hip_runtime.h>
#include <cmath>

typedef short short8 __attribute__((ext_vector_type(8)));
typedef float floatx4 __attribute__((ext_vector_type(4)));

#define T_LEN 4096
#define HC 256
#define NPOS (32 * 4096)
#define OUT_ELEMS (32 * 4 * 4096)

__device__ __forceinline__ ushort f2bf(float f) {
    uint u = __float_as_uint(f);
    u += 0x7FFFu + ((u >> 16) & 1u);
    return (ushort)(u >> 16);
}
__device__ __forceinline__ float bf2f(ushort u) {
    return __uint_as_float(((uint)u) << 16);
}
__device__ __forceinline__ uint addbf2(uint a, uint b) {
    const float lo = bf2f((ushort)(a & 0xffffu)) + bf2f((ushort)(b & 0xffffu));
    const float hi = bf2f((ushort)(a >> 16)) + bf2f((ushort)(b >> 16));
    return (uint)f2bf(lo) | ((uint)f2bf(hi) << 16);
}
// add bf16-pair y to two already-bf16-rounded floats ha/hb, repack
__device__ __forceinline__ uint addbf2f(uint y, float ha, float hb) {
    const float lo = bf2f((ushort)(y & 0xffffu)) + ha;
    const float hi = bf2f((ushort)(y >> 16)) + hb;
    return (uint)f2bf(lo) | ((uint)f2bf(hi) << 16);
}
// fast tanh-form gelu: 8 instr, no branches; |err vs exact-erf gelu| <~1.5e-3
__device__ __forceinline__ float gelu_f(float x) {
    const float x2 = x * x;
    const float w = fmaf(0.044715f * x2, x, x);
    const float e = __builtin_amdgcn_exp2f(2.3022084f * w);
    const float r = __builtin_amdgcn_rcpf(1.f + e);
    return fmaf(-x, r, x);
}
__device__ __forceinline__ float softplus_f(float x) {
    return (x > 20.f) ? x : log1pf(expf(x));
}
__device__ __forceinline__ void unpack8(uint4 r, float m, float* o) {
    o[0] = bf2f((ushort)(r.x & 0xffffu)) * m;
    o[1] = bf2f((ushort)(r.x >> 16)) * m;
    o[2] = bf2f((ushort)(r.y & 0xffffu)) * m;
    o[3] = bf2f((ushort)(r.y >> 16)) * m;
    o[4] = bf2f((ushort)(r.z & 0xffffu)) * m;
    o[5] = bf2f((ushort)(r.z >> 16)) * m;
    o[6] = bf2f((ushort)(r.w & 0xffffu)) * m;
    o[7] = bf2f((ushort)(r.w >> 16)) * m;
}
__device__ __forceinline__ void load8bf(const ushort* p, float m, float* o) {
    unpack8(*(const uint4*)p, m, o);
}

// ---------------------------------------------------------------- prep ----
__global__ __launch_bounds__(256) void prep_kernel(
    const float* __restrict__ cw, const float* __restrict__ pw,
    const float* __restrict__ x, const float* __restrict__ mask,
    ushort* __restrict__ wbf, ushort* __restrict__ pwbf,
    float* __restrict__ out)
{
    int idx = blockIdx.x * 256 + threadIdx.x;
    if (idx < 262144) {
        wbf[idx] = f2bf(cw[idx]);
    } else if (idx < 262144 + 16384) {
        int j = idx - 262144;
        int row = j >> 8, c = j & 255;
        pwbf[j] = (row < 58) ? f2bf(pw[row * 256 + c]) : (ushort)0;
    } else if (idx < 262144 + 16384 + 262144) {
        int j = idx - 278528;
        int b = j >> 13;
        int r = j & 8191;
        int ch = r >> 12;
        int t = r & 4095;
        out[b * 16384 + ch * 4096 + t] =
            x[b * 16384 + ch * 4096 + t] * mask[b * 4096 + t];
    } else if (idx < 262144 + 16384 + 262144 + 32) {
        out[OUT_ELEMS + (idx - 540672)] = 0.f;
    }
}

// -------------------------------------------------------------- fused0 ----
// (R2 — known good, 547.9us total) Layer 0 fully fused, residual recomputed
// in epilogue (no hg stream). R3's prefetch experiments spilled to scratch
// (WRITE_SIZE 67->147MB) — register file is full during MFMA; do NOT hold
// prefetched state across phase boundaries.
__global__ __launch_bounds__(256, 3) void fused0_kernel(
    const float* __restrict__ x,
    ushort* __restrict__ hout, const ushort* __restrict__ wbf,
    const float* __restrict__ pre_w, const float* __restrict__ pre_b,
    const float* __restrict__ sep_w, const float* __restrict__ sep_b,
    const float* __restrict__ conv1_b,
    const float* __restrict__ n1g, const float* __restrict__ n1b,
    const float* __restrict__ n2g, const float* __restrict__ n2b,
    const float* __restrict__ mask)
{
    __shared__ __align__(16) ushort ylds[64 * 264];
    __shared__ float ssum[64][2];
    __shared__ float ssq[64][2];

    const int tid = threadIdx.x;
    const int lane = tid & 63;
    const int wv = tid >> 6;
    const int P = blockIdx.x;
    const int L = (P & 7) * 256 + (P >> 3);
    const int b = L >> 6;
    const int t0 = (L & 63) << 6;
    const float* maskb = mask + b * T_LEN;
    const float* xb0 = x + b * 16384;
    const float* xb1 = x + b * 16384 + 4096;
    const size_t hbase = (size_t)b * T_LEN * HC;

    // ---- phase 1: h from x + dwconv(1) + LN(n1) + gelu -> ylds ----
    {
        const int half = lane >> 5;
        const int ln32 = lane & 31;
        const int c0 = ln32 * 8;
        float w0[8], w1[8];
        #pragma unroll
        for (int j = 0; j < 4; ++j) {
            float4 wv4 = *(const float4*)(pre_w + c0 * 2 + 4 * j);
            w0[2 * j] = wv4.x; w1[2 * j] = wv4.y;
            w0[2 * j + 1] = wv4.z; w1[2 * j + 1] = wv4.w;
        }
        float pbv[8];
        *(float4*)(pbv + 0) = *(const float4*)(pre_b + c0);
        *(float4*)(pbv + 4) = *(const float4*)(pre_b + c0 + 4);
        float sw[24];
        #pragma unroll
        for (int j = 0; j < 6; ++j)
            *(float4*)(sw + 4 * j) = *(const float4*)(sep_w + c0 * 3 + 4 * j);
        float sbv[8], g1v[8], b1v[8];
        *(float4*)(sbv + 0) = *(const float4*)(sep_b + c0);
        *(float4*)(sbv + 4) = *(const float4*)(sep_b + c0 + 4);
        *(float4*)(g1v + 0) = *(const float4*)(n1g + c0);
        *(float4*)(g1v + 4) = *(const float4*)(n1g + c0 + 4);
        *(float4*)(b1v + 0) = *(const float4*)(n1b + c0);
        *(float4*)(b1v + 4) = *(const float4*)(n1b + c0 + 4);

        for (int mm = 0; mm < 8; ++mm) {
            const int rloc = wv * 16 + mm * 2 + half;
            const int t = t0 + rloc;
            const float xa = xb0[t], xc = xb1[t];
            const float mc = maskb[t];
            float xam = 0.f, xcm = 0.f, mmk = 0.f;
            float xap = 0.f, xcp = 0.f, mpk = 0.f;
            if (t >= 1) { xam = xb0[t - 1]; xcm = xb1[t - 1]; mmk = maskb[t - 1]; }
            if (t + 1 < T_LEN) { xap = xb0[t + 1]; xcp = xb1[t + 1]; mpk = maskb[t + 1]; }

            float v[8];
            float s = 0.f, q = 0.f;
            #pragma unroll
            for (int j = 0; j < 8; ++j) {
                const float hcj = fmaf(w0[j], xa, fmaf(w1[j], xc, pbv[j]));
                const float hmj = fmaf(w0[j], xam, fmaf(w1[j], xcm, pbv[j])) * mmk;
                const float hpj = fmaf(w0[j], xap, fmaf(w1[j], xcp, pbv[j])) * mpk;
                const float vv = sw[3 * j] * hmj + sw[3 * j + 1] * (hcj * mc)
                               + sw[3 * j + 2] * hpj + sbv[j];
                v[j] = vv;
                s += vv;
                q += vv * vv;
            }
            #pragma unroll
            for (int d = 16; d > 0; d >>= 1) {
                s += __shfl_xor(s, d, 64);
                q += __shfl_xor(q, d, 64);
            }
            const float mean = s * (1.f / 256.f);
            const float var = q * (1.f / 256.f) - mean * mean;
            const float rs = rsqrtf(var + 1e-5f);
            uint pk[4];
            #pragma unroll
            for (int j = 0; j < 4; ++j) {
                const float ya = gelu_f((v[2 * j] - mean) * rs * g1v[2 * j] + b1v[2 * j]);
                const float yb = gelu_f((v[2 * j + 1] - mean) * rs * g1v[2 * j + 1] + b1v[2 * j + 1]);
                pk[j] = (uint)f2bf(ya) | ((uint)f2bf(yb) << 16);
            }
            *(uint4*)(&ylds[rloc * 264 + c0]) = make_uint4(pk[0], pk[1], pk[2], pk[3]);
        }
    }
    __syncthreads();

    // ---- phase 2: pipelined MFMA, A from LDS ----
    const int lw = lane & 15;
    const int quad = lane >> 4;
    const int mh = wv >> 1;
    const int nh = wv & 1;
    floatx4 acc[2][8];
    #pragma unroll
    for (int m = 0; m < 2; ++m)
        #pragma unroll
        for (int n = 0; n < 8; ++n) acc[m][n] = (floatx4){0.f, 0.f, 0.f, 0.f};

    const ushort* wb = wbf + (nh * 128 + lw) * 256 + quad * 8;
    const ushort* la0 = &ylds[(mh * 32 + lw) * 264 + quad * 8];
    const ushort* la1 = &ylds[(mh * 32 + 16 + lw) * 264 + quad * 8];

    short8 a0c = *(const short8*)(la0);
    short8 a1c = *(const short8*)(la1);
    short8 bcur[8], bnx[8];
    #pragma unroll
    for (int n = 0; n < 8; ++n)
        bcur[n] = *(const short8*)(wb + n * 4096);

    short8 a0n, a1n;
    #pragma unroll
    for (int kt = 0; kt < 8; ++kt) {
        if (kt < 7) {
            a0n = *(const short8*)(la0 + (kt + 1) * 32);
            a1n = *(const short8*)(la1 + (kt + 1) * 32);
            #pragma unroll
            for (int n = 0; n < 8; ++n)
                bnx[n] = *(const short8*)(wb + n * 4096 + (kt + 1) * 32);
        }
        #pragma unroll
        for (int n = 0; n < 8; ++n) {
            acc[0][n] = __builtin_amdgcn_mfma_f32_16x16x32_bf16(a0c, bcur[n], acc[0][n], 0, 0, 0);
            acc[1][n] = __builtin_amdgcn_mfma_f32_16x16x32_bf16(a1c, bcur[n], acc[1][n], 0, 0, 0);
        }
        a0c = a0n;
        a1c = a1n;
        #pragma unroll
        for (int n = 0; n < 8; ++n) bcur[n] = bnx[n];
    }

    float sum[2][4] = {{0, 0, 0, 0}, {0, 0, 0, 0}};
    float sq[2][4] = {{0, 0, 0, 0}, {0, 0, 0, 0}};
    #pragma unroll
    for (int n = 0; n < 8; ++n) {
        const float cb = conv1_b[nh * 128 + n * 16 + lw];
        #pragma unroll
        for (int m = 0; m < 2; ++m)
            #pragma unroll
            for (int r = 0; r < 4; ++r) {
                const float val = acc[m][n][r] + cb;
                acc[m][n][r] = val;
                sum[m][r] += val;
                sq[m][r] += val * val;
            }
    }
    #pragma unroll
    for (int d = 1; d < 16; d <<= 1) {
        #pragma unroll
        for (int m = 0; m < 2; ++m)
            #pragma unroll
            for (int r = 0; r < 4; ++r) {
                sum[m][r] += __shfl_xor(sum[m][r], d, 64);
                sq[m][r] += __shfl_xor(sq[m][r], d, 64);
            }
    }
    if (lw == 0) {
        #pragma unroll
        for (int m = 0; m < 2; ++m)
            #pragma unroll
            for (int r = 0; r < 4; ++r) {
                ssum[mh * 32 + m * 16 + quad * 4 + r][nh] = sum[m][r];
                ssq[mh * 32 + m * 16 + quad * 4 + r][nh] = sq[m][r];
            }
    }
    __syncthreads();

    float mean[2][4], rsv[2][4];
    #pragma unroll
    for (int m = 0; m < 2; ++m)
        #pragma unroll
        for (int r = 0; r < 4; ++r) {
            const int row = mh * 32 + m * 16 + quad * 4 + r;
            const float s = ssum[row][0] + ssum[row][1];
            const float q = ssq[row][0] + ssq[row][1];
            mean[m][r] = s * (1.f / 256.f);
            const float var = q * (1.f / 256.f) - mean[m][r] * mean[m][r];
            rsv[m][r] = rsqrtf(var + 1e-5f);
        }
    #pragma unroll
    for (int n = 0; n < 8; ++n) {
        const int o = nh * 128 + n * 16 + lw;
        const float g2 = n2g[o], b2 = n2b[o];
        #pragma unroll
        for (int m = 0; m < 2; ++m)
            #pragma unroll
            for (int r = 0; r < 4; ++r) {
                const int row = mh * 32 + m * 16 + quad * 4 + r;
                const float y = gelu_f((acc[m][n][r] - mean[m][r]) * rsv[m][r] * g2 + b2);
                ylds[row * 264 + o] = f2bf(y);
            }
    }
    __syncthreads();

    // ---- epilogue: recompute residual h from x (bf16-rounded), add y ----
    {
        const int half = lane >> 5;
        const int ln32 = lane & 31;
        const int c0 = ln32 * 8;
        float w0[8], w1[8], pbv[8];
        #pragma unroll
        for (int j = 0; j < 4; ++j) {
            float4 wv4 = *(const float4*)(pre_w + c0 * 2 + 4 * j);
            w0[2 * j] = wv4.x; w1[2 * j] = wv4.y;
            w0[2 * j + 1] = wv4.z; w1[2 * j + 1] = wv4.w;
        }
        *(float4*)(pbv + 0) = *(const float4*)(pre_b + c0);
        *(float4*)(pbv + 4) = *(const float4*)(pre_b + c0 + 4);
        #pragma unroll
        for (int mm = 0; mm < 8; ++mm) {
            const int rloc = wv * 16 + mm * 2 + half;
            const int t = t0 + rloc;
            const float xa = xb0[t], xc = xb1[t];
            const uint4 yv = *(const uint4*)(&ylds[rloc * 264 + c0]);
            uint ov[4];
            const uint yw[4] = {yv.x, yv.y, yv.z, yv.w};
            #pragma unroll
            for (int j = 0; j < 4; ++j) {
                const float ha = bf2f(f2bf(fmaf(w0[2 * j], xa, fmaf(w1[2 * j], xc, pbv[2 * j]))));
                const float hb = bf2f(f2bf(fmaf(w0[2 * j + 1], xa, fmaf(w1[2 * j + 1], xc, pbv[2 * j + 1]))));
                ov[j] = addbf2f(yw[j], ha, hb);
            }
            *(uint4*)(hout + hbase + (size_t)t * HC + c0) =
                make_uint4(ov[0], ov[1], ov[2], ov[3]);
        }
    }
}

// --------------------------------------------------------------- fused ----
// (R2 — known good) Layers 1-3: dwconv+LN+gelu -> ylds, pipelined MFMA,
// LN(n2)+gelu+residual -> hout. Ping-pong, never in-place. Center taps
// issued upfront as transient hraw[8] (dead before MFMA — no spill).
__global__ __launch_bounds__(256, 3) void fused_kernel(
    const ushort* __restrict__ hin, ushort* __restrict__ hout,
    const ushort* __restrict__ wbf,
    const float* __restrict__ sep_w, const float* __restrict__ sep_b,
    const float* __restrict__ conv1_b,
    const float* __restrict__ n1g, const float* __restrict__ n1b,
    const float* __restrict__ n2g, const float* __restrict__ n2b,
    const float* __restrict__ mask, int dil)
{
    __shared__ __align__(16) ushort ylds[64 * 264];
    __shared__ float ssum[64][2];
    __shared__ float ssq[64][2];

    const int tid = threadIdx.x;
    const int lane = tid & 63;
    const int wv = tid >> 6;
    const int P = blockIdx.x;
    const int L = (P & 7) * 256 + (P >> 3);
    const int b = L >> 6;
    const int t0 = (L & 63) << 6;
    const float* maskb = mask + b * T_LEN;
    const size_t hbase = (size_t)b * T_LEN * HC;

    {
        const int half = lane >> 5;
        const int ln32 = lane & 31;
        const int c0 = ln32 * 8;
        float sw[24];
        #pragma unroll
        for (int j = 0; j < 6; ++j)
            *(float4*)(sw + 4 * j) = *(const float4*)(sep_w + c0 * 3 + 4 * j);
        float sbv[8], g1v[8], b1v[8];
        *(float4*)(sbv + 0) = *(const float4*)(sep_b + c0);
        *(float4*)(sbv + 4) = *(const float4*)(sep_b + c0 + 4);
        *(float4*)(g1v + 0) = *(const float4*)(n1g + c0);
        *(float4*)(g1v + 4) = *(const float4*)(n1g + c0 + 4);
        *(float4*)(b1v + 0) = *(const float4*)(n1b + c0);
        *(float4*)(b1v + 4) = *(const float4*)(n1b + c0 + 4);

        // issue all 8 center-tap loads upfront (MLP across mm iterations)
        uint4 hraw[8];
        #pragma unroll
        for (int mm = 0; mm < 8; ++mm) {
            const int t = t0 + wv * 16 + mm * 2 + half;
            hraw[mm] = *(const uint4*)(hin + hbase + (size_t)t * HC + c0);
        }

        for (int mm = 0; mm < 8; ++mm) {
            const int rloc = wv * 16 + mm * 2 + half;
            const int t = t0 + rloc;
            float hm[8] = {0, 0, 0, 0, 0, 0, 0, 0};
            float hp[8] = {0, 0, 0, 0, 0, 0, 0, 0};
            float hc[8];
            unpack8(hraw[mm], maskb[t], hc);
            if (t >= dil)
                load8bf(hin + hbase + (size_t)(t - dil) * HC + c0, maskb[t - dil], hm);
            if (t + dil < T_LEN)
                load8bf(hin + hbase + (size_t)(t + dil) * HC + c0, maskb[t + dil], hp);
            float v[8];
            float s = 0.f, q = 0.f;
            #pragma unroll
            for (int j = 0; j < 8; ++j) {
                const float vv = sw[3 * j] * hm[j] + sw[3 * j + 1] * hc[j]
                               + sw[3 * j + 2] * hp[j] + sbv[j];
                v[j] = vv;
                s += vv;
                q += vv * vv;
            }
            #pragma unroll
            for (int d = 16; d > 0; d >>= 1) {
                s += __shfl_xor(s, d, 64);
                q += __shfl_xor(q, d, 64);
            }
            const float mean = s * (1.f / 256.f);
            const float var = q * (1.f / 256.f) - mean * mean;
            const float rs = rsqrtf(var + 1e-5f);
            uint pk[4];
            #pragma unroll
            for (int j = 0; j < 4; ++j) {
                const float ya = gelu_f((v[2 * j] - mean) * rs * g1v[2 * j] + b1v[2 * j]);
                const float yb = gelu_f((v[2 * j + 1] - mean) * rs * g1v[2 * j + 1] + b1v[2 * j + 1]);
                pk[j] = (uint)f2bf(ya) | ((uint)f2bf(yb) << 16);
            }
            *(uint4*)(&ylds[rloc * 264 + c0]) = make_uint4(pk[0], pk[1], pk[2], pk[3]);
        }
    }
    __syncthreads();

    const int lw = lane & 15;
    const int quad = lane >> 4;
    const int mh = wv >> 1;
    const int nh = wv & 1;
    floatx4 acc[2][8];
    #pragma unroll
    for (int m = 0; m < 2; ++m)
        #pragma unroll
        for (int n = 0; n < 8; ++n) acc[m][n] = (floatx4){0.f, 0.f, 0.f, 0.f};

    const ushort* wb = wbf + (nh * 128 + lw) * 256 + quad * 8;
    const ushort* la0 = &ylds[(mh * 32 + lw) * 264 + quad * 8];
    const ushort* la1 = &ylds[(mh * 32 + 16 + lw) * 264 + quad * 8];

    short8 a0c = *(const short8*)(la0);
    short8 a1c = *(const short8*)(la1);
    short8 bcur[8], bnx[8];
    #pragma unroll
    for (int n = 0; n < 8; ++n)
        bcur[n] = *(const short8*)(wb + n * 4096);

    short8 a0n, a1n;
    #pragma unroll
    for (int kt = 0; kt < 8; ++kt) {
        if (kt < 7) {
            a0n = *(const short8*)(la0 + (kt + 1) * 32);
            a1n = *(const short8*)(la1 + (kt + 1) * 32);
            #pragma unroll
            for (int n = 0; n < 8; ++n)
                bnx[n] = *(const short8*)(wb + n * 4096 + (kt + 1) * 32);
        }
        #pragma unroll
        for (int n = 0; n < 8; ++n) {
            acc[0][n] = __builtin_amdgcn_mfma_f32_16x16x32_bf16(a0c, bcur[n], acc[0][n], 0, 0, 0);
            acc[1][n] = __builtin_amdgcn_mfma_f32_16x16x32_bf16(a1c, bcur[n], acc[1][n], 0, 0, 0);
        }
        a0c = a0n;
        a1c = a1n;
        #pragma unroll
        for (int n = 0; n < 8; ++n) bcur[n] = bnx[n];
    }

    uint4 hv[8];
    #pragma unroll
    for (int jj = 0; jj < 8; ++jj) {
        const int idx = jj * 256 + tid;
        const int row = idx >> 5, seg = idx & 31;
        hv[jj] = *(const uint4*)(hin + hbase + (size_t)(t0 + row) * HC + seg * 8);
    }

    float sum[2][4] = {{0, 0, 0, 0}, {0, 0, 0, 0}};
    float sq[2][4] = {{0, 0, 0, 0}, {0, 0, 0, 0}};
    #pragma unroll
    for (int n = 0; n < 8; ++n) {
        const float cb = conv1_b[nh * 128 + n * 16 + lw];
        #pragma unroll
        for (int m = 0; m < 2; ++m)
            #pragma unroll
            for (int r = 0; r < 4; ++r) {
                const float val = acc[m][n][r] + cb;
                acc[m][n][r] = val;
                sum[m][r] += val;
                sq[m][r] += val * val;
            }
    }
    #pragma unroll
    for (int d = 1; d < 16; d <<= 1) {
        #pragma unroll
        for (int m = 0; m < 2; ++m)
            #pragma unroll
            for (int r = 0; r < 4; ++r) {
                sum[m][r] += __shfl_xor(sum[m][r], d, 64);
                sq[m][r] += __shfl_xor(sq[m][r], d, 64);
            }
    }
    if (lw == 0) {
        #pragma unroll
        for (int m = 0; m < 2; ++m)
            #pragma unroll
            for (int r = 0; r < 4; ++r) {
                ssum[mh * 32 + m * 16 + quad * 4 + r][nh] = sum[m][r];
                ssq[mh * 32 + m * 16 + quad * 4 + r][nh] = sq[m][r];
            }
    }
    __syncthreads();

    float mean[2][4], rsv[2][4];
    #pragma unroll
    for (int m = 0; m < 2; ++m)
        #pragma unroll
        for (int r = 0; r < 4; ++r) {
            const int row = mh * 32 + m * 16 + quad * 4 + r;
            const float s = ssum[row][0] + ssum[row][1];
            const float q = ssq[row][0] + ssq[row][1];
            mean[m][r] = s * (1.f / 256.f);
            const float var = q * (1.f / 256.f) - mean[m][r] * mean[m][r];
            rsv[m][r] = rsqrtf(var + 1e-5f);
        }
    #pragma unroll
    for (int n = 0; n < 8; ++n) {
        const int o = nh * 128 + n * 16 + lw;
        const float g2 = n2g[o], b2 = n2b[o];
        #pragma unroll
        for (int m = 0; m < 2; ++m)
            #pragma unroll
            for (int r = 0; r < 4; ++r) {
                const int row = mh * 32 + m * 16 + quad * 4 + r;
                const float y = gelu_f((acc[m][n][r] - mean[m][r]) * rsv[m][r] * g2 + b2);
                ylds[row * 264 + o] = f2bf(y);
            }
    }
    __syncthreads();

    #pragma unroll
    for (int jj = 0; jj < 8; ++jj) {
        const int idx = jj * 256 + tid;
        const int row = idx >> 5, seg = idx & 31;
        const size_t g = hbase + (size_t)(t0 + row) * HC + seg * 8;
        const uint4 yv = *(const uint4*)(&ylds[row * 264 + seg * 8]);
        uint4 ov;
        ov.x = addbf2(yv.x, hv[jj].x);
        ov.y = addbf2(yv.y, hv[jj].y);
        ov.z = addbf2(yv.z, hv[jj].z);
        ov.w = addbf2(yv.w, hv[jj].w);
        *(uint4*)(hout + g) = ov;
    }
}

// ---------------------------------------------------------- proj+spline ----
// LDS union: slds (16.6KB) aliases alds (33.8KB); exch (5.5KB) uses the
// alds tail beyond slds — all alds reads complete before reuse.
// vs R2: the spline prologue is split across thread PAIRS — thread i (A)
// computes both softmax/cumsum chains while thread i+128 (B) concurrently
// computes the 9 softplus derivatives (18 transcendentals) and passes them
// via exch. Previously 128 threads idled through this section.
__global__ __launch_bounds__(256, 4) void proj_kernel(
    const ushort* __restrict__ hin, const ushort* __restrict__ pwbf,
    const float* __restrict__ projb, const float* __restrict__ x,
    const float* __restrict__ mask, float* __restrict__ out)
{
    __shared__ __align__(16) ushort alds[64 * 264];
    __shared__ float red[4];
    float* slds = reinterpret_cast<float*>(alds);          // 64 x 65 floats
    float* exch = reinterpret_cast<float*>(alds) + 64 * 65; // 128 x 11 floats (stride 11: bank-safe)

    const int tid = threadIdx.x;
    const int lane = tid & 63;
    const int wv = tid >> 6;
    const int blk = blockIdx.x;
    const int b = blk >> 6;
    const int t0 = (blk & 63) << 6;
    const size_t hbase = (size_t)b * T_LEN * HC;

    #pragma unroll
    for (int jj = 0; jj < 8; ++jj) {
        const int idx = jj * 256 + tid;
        const int row = idx >> 5, seg = idx & 31;
        short8 v = *(const short8*)(hin + hbase + (size_t)(t0 + row) * HC + seg * 8);
        *(short8*)(&alds[row * 264 + seg * 8]) = v;
    }
    __syncthreads();

    const int lw = lane & 15;
    const int quad = lane >> 4;
    floatx4 acc[4];
    #pragma unroll
    for (int n = 0; n < 4; ++n) acc[n] = (floatx4){0.f, 0.f, 0.f, 0.f};
    #pragma unroll
    for (int kt = 0; kt < 8; ++kt) {
        short8 a = *(short8*)(&alds[(wv * 16 + lw) * 264 + kt * 32 + quad * 8]);
        #pragma unroll
        for (int n = 0; n < 4; ++n) {
            short8 bb = *(const short8*)(pwbf + (n * 16 + lw) * 256 + kt * 32 + quad * 8);
            acc[n] = __builtin_amdgcn_mfma_f32_16x16x32_bf16(a, bb, acc[n], 0, 0, 0);
        }
    }
    __syncthreads();   // all alds reads done -> safe to reuse as slds/exch
    #pragma unroll
    for (int n = 0; n < 4; ++n) {
        const int o = n * 16 + lw;
        const float pb = (o < 58) ? projb[o] : 0.f;
        #pragma unroll
        for (int r = 0; r < 4; ++r) {
            const int row = wv * 16 + quad * 4 + r;
            const float mv = mask[b * T_LEN + t0 + row];
            slds[row * 65 + o] = acc[n][r] * mv + pb;
        }
    }
    __syncthreads();

    const int item = tid & 127;
    const int pos = item >> 1;
    const int ch = item & 1;
    const int t = t0 + pos;
    const bool isA = tid < 128;
    const float SC = 0.0625f;

    float cwv[11], wdv[10], chv[11], htv[10];
    float x1 = 0.f, mv = 0.f;

    if (!isA) {
        // ---- B: 9 softplus derivatives -> exch ----
        #pragma unroll
        for (int j = 1; j <= 9; ++j) {
            const float u = slds[pos * 65 + ch * 29 + 19 + j];
            exch[item * 11 + (j - 1)] = 0.001f + softplus_f(u);
        }
    } else {
        // ---- A: both softmax/cumsum chains (registers, live across barrier) ----
        x1 = x[b * 16384 + (2 + ch) * 4096 + t];
        mv = mask[b * T_LEN + t];
        float svA[20];
        #pragma unroll
        for (int j = 0; j < 20; ++j) svA[j] = slds[pos * 65 + ch * 29 + j];
        {
            float u[10];
            float mx = -1e30f;
            #pragma unroll
            for (int j = 0; j < 10; ++j) { u[j] = svA[j] * SC; mx = fmaxf(mx, u[j]); }
            float ssm = 0.f;
            #pragma unroll
            for (int j = 0; j < 10; ++j) { u[j] = expf(u[j] - mx); ssm += u[j]; }
            const float inv = 1.f / ssm;
            float cum = 0.f;
            cwv[0] = -5.f;
            #pragma unroll
            for (int j = 0; j < 10; ++j) {
                cum += 0.001f + 0.99f * u[j] * inv;
                cwv[j + 1] = 10.f * cum - 5.f;
            }
            cwv[10] = 5.f;
            #pragma unroll
            for (int j = 0; j < 10; ++j) wdv[j] = cwv[j + 1] - cwv[j];
        }
        {
            float u[10];
            float mx = -1e30f;
            #pragma unroll
            for (int j = 0; j < 10; ++j) { u[j] = svA[10 + j] * SC; mx = fmaxf(mx, u[j]); }
            float ssm = 0.f;
            #pragma unroll
            for (int j = 0; j < 10; ++j) { u[j] = expf(u[j] - mx); ssm += u[j]; }
            const float inv = 1.f / ssm;
            float cum = 0.f;
            chv[0] = -5.f;
            #pragma unroll
            for (int j = 0; j < 10; ++j) {
                cum += 0.001f + 0.99f * u[j] * inv;
                chv[j + 1] = 10.f * cum - 5.f;
            }
            chv[10] = 5.f;
            #pragma unroll
            for (int j = 0; j < 10; ++j) htv[j] = chv[j + 1] - chv[j];
        }
    }
    __syncthreads();   // B's exch visible to A

    float contrib = 0.f;
    if (isA) {
        float dvv[11];
        dvv[0] = 1.f;
        dvv[10] = 1.f;
        #pragma unroll
        for (int j = 1; j <= 9; ++j) dvv[j] = exch[item * 11 + (j - 1)];

        const bool inside = (x1 >= -5.f) && (x1 <= 5.f);
        const float xc = fminf(fmaxf(x1, -5.f), 5.f);
        float in_cw = cwv[0], in_w = wdv[0], in_ch = chv[0], in_h = htv[0];
        float dk = dvv[0], dk1 = dvv[1];
        #pragma unroll
        for (int j = 1; j < 10; ++j) {
            const bool ge = (xc >= cwv[j]);
            in_cw = ge ? cwv[j] : in_cw;
            in_w  = ge ? wdv[j] : in_w;
            in_ch = ge ? chv[j] : in_ch;
            in_h  = ge ? htv[j] : in_h;
            dk    = ge ? dvv[j] : dk;
            dk1   = ge ? dvv[j + 1] : dk1;
        }
        const float th = (xc - in_cw) / in_w;
        const float t1m = th * (1.f - th);
        const float dl = in_h / in_w;
        const float num = in_h * (dl * th * th + dk * t1m);
        const float den = dl + (dk + dk1 - 2.f * dl) * t1m;
        float yv = in_ch + num / den;
        const float omt = 1.f - th;
        const float dnum = dl * dl * (dk1 * th * th + 2.f * dl * t1m + dk * omt * omt);
        float lad = logf(dnum) - 2.f * logf(den);
        if (!inside) { yv = x1; lad = 0.f; }
        out[b * 16384 + (2 + ch) * 4096 + t] = yv * mv;
        contrib = lad * mv;
    }
    #pragma unroll
    for (int d = 32; d > 0; d >>= 1) contrib += __shfl_xor(contrib, d, 64);
    if (lane == 0) red[wv] = contrib;
    __syncthreads();
    if (tid == 0) atomicAdd(out + OUT_ELEMS + b, red[0] + red[1] + red[2] + red[3]);
}

// -------------------------------------------------------------- launch ----
extern "C" void kernel_launch(void* const* d_in, const int* in_sizes, int n_in,
                              void* d_out, int out_size, void* d_ws, size_t ws_size,
                              hipStream_t stream) {
    const float* x      = (const float*)d_in[0];
    const float* mask   = (const float*)d_in[1];
    const float* pre_w  = (const float*)d_in[2];
    const float* pre_b  = (const float*)d_in[3];
    const float* sep_w  = (const float*)d_in[4];
    const float* sep_b  = (const float*)d_in[5];
    const float* conv1w = (const float*)d_in[6];
    const float* conv1b = (const float*)d_in[7];
    const float* n1g    = (const float*)d_in[8];
    const float* n1b    = (const float*)d_in[9];
    const float* n2g    = (const float*)d_in[10];
    const float* n2b    = (const float*)d_in[11];
    const float* projw  = (const float*)d_in[12];
    const float* projb  = (const float*)d_in[13];
    float* out = (float*)d_out;

    ushort* h0   = (ushort*)d_ws;
    ushort* h1   = h0 + (size_t)NPOS * HC;
    ushort* wbf  = h1 + (size_t)NPOS * HC;
    ushort* pwbf = wbf + 4 * 256 * 256;

    prep_kernel<<<2113, 256, 0, stream>>>(conv1w, projw, x, mask, wbf, pwbf, out);

    // layer 0: fully fused, residual recomputed in epilogue (no hg stream)
    fused0_kernel<<<2048, 256, 0, stream>>>(x, h1, wbf,
        pre_w, pre_b, sep_w, sep_b, conv1b, n1g, n1b, n2g, n2b, mask);

    // layers 1-3: fully fused (y stays in LDS); ping-pong, never in-place
    fused_kernel<<<2048, 256, 0, stream>>>(h1, h0, wbf + 1 * 65536,
        sep_w + 1 * 768, sep_b + 1 * 256, conv1b + 1 * 256,
        n1g + 1 * 256, n1b + 1 * 256, n2g + 1 * 256, n2b + 1 * 256, mask, 3);
    fused_kernel<<<2048, 256, 0, stream>>>(h0, h1, wbf + 2 * 65536,
        sep_w + 2 * 768, sep_b + 2 * 256, conv1b + 2 * 256,
        n1g + 2 * 256, n1b + 2 * 256, n2g + 2 * 256, n2b + 2 * 256, mask, 9);
    fused_kernel<<<2048, 256, 0, stream>>>(h1, h0, wbf + 3 * 65536,
        sep_w + 3 * 768, sep_b + 3 * 256, conv1b + 3 * 256,
        n1g + 3 * 256, n1b + 3 * 256, n2g + 3 * 256, n2b + 3 * 256, mask, 27);

    proj_kernel<<<2048, 256, 0, stream>>>(h0, pwbf, projb, x, mask, out);
}

// Round 5
// 524.572 us; speedup vs baseline: 1.1784x; 1.0432x over previous
//
#include <hip/hip_runtime.h>
#include <cmath>

typedef short short8 __attribute__((ext_vector_type(8)));
typedef float floatx4 __attribute__((ext_vector_type(4)));

#define T_LEN 4096
#define HC 256
#define NPOS (32 * 4096)
#define OUT_ELEMS (32 * 4 * 4096)

__device__ __forceinline__ ushort f2bf(float f) {
    uint u = __float_as_uint(f);
    u += 0x7FFFu + ((u >> 16) & 1u);
    return (ushort)(u >> 16);
}
__device__ __forceinline__ float bf2f(ushort u) {
    return __uint_as_float(((uint)u) << 16);
}
__device__ __forceinline__ uint addbf2(uint a, uint b) {
    const float lo = bf2f((ushort)(a & 0xffffu)) + bf2f((ushort)(b & 0xffffu));
    const float hi = bf2f((ushort)(a >> 16)) + bf2f((ushort)(b >> 16));
    return (uint)f2bf(lo) | ((uint)f2bf(hi) << 16);
}
// add bf16-pair y to two already-bf16-rounded floats ha/hb, repack
__device__ __forceinline__ uint addbf2f(uint y, float ha, float hb) {
    const float lo = bf2f((ushort)(y & 0xffffu)) + ha;
    const float hi = bf2f((ushort)(y >> 16)) + hb;
    return (uint)f2bf(lo) | ((uint)f2bf(hi) << 16);
}
// fast tanh-form gelu: 8 instr, no branches; |err vs exact-erf gelu| <~1.5e-3
__device__ __forceinline__ float gelu_f(float x) {
    const float x2 = x * x;
    const float w = fmaf(0.044715f * x2, x, x);
    const float e = __builtin_amdgcn_exp2f(2.3022084f * w);
    const float r = __builtin_amdgcn_rcpf(1.f + e);
    return fmaf(-x, r, x);
}
__device__ __forceinline__ float softplus_f(float x) {
    return (x > 20.f) ? x : log1pf(expf(x));
}
__device__ __forceinline__ void unpack8(uint4 r, float m, float* o) {
    o[0] = bf2f((ushort)(r.x & 0xffffu)) * m;
    o[1] = bf2f((ushort)(r.x >> 16)) * m;
    o[2] = bf2f((ushort)(r.y & 0xffffu)) * m;
    o[3] = bf2f((ushort)(r.y >> 16)) * m;
    o[4] = bf2f((ushort)(r.z & 0xffffu)) * m;
    o[5] = bf2f((ushort)(r.z >> 16)) * m;
    o[6] = bf2f((ushort)(r.w & 0xffffu)) * m;
    o[7] = bf2f((ushort)(r.w >> 16)) * m;
}
__device__ __forceinline__ void load8bf(const ushort* p, float m, float* o) {
    unpack8(*(const uint4*)p, m, o);
}

// ---------------------------------------------------------------- prep ----
__global__ __launch_bounds__(256) void prep_kernel(
    const float* __restrict__ cw, const float* __restrict__ pw,
    const float* __restrict__ x, const float* __restrict__ mask,
    ushort* __restrict__ wbf, ushort* __restrict__ pwbf,
    float* __restrict__ out)
{
    int idx = blockIdx.x * 256 + threadIdx.x;
    if (idx < 262144) {
        wbf[idx] = f2bf(cw[idx]);
    } else if (idx < 262144 + 16384) {
        int j = idx - 262144;
        int row = j >> 8, c = j & 255;
        pwbf[j] = (row < 58) ? f2bf(pw[row * 256 + c]) : (ushort)0;
    } else if (idx < 262144 + 16384 + 262144) {
        int j = idx - 278528;
        int b = j >> 13;
        int r = j & 8191;
        int ch = r >> 12;
        int t = r & 4095;
        out[b * 16384 + ch * 4096 + t] =
            x[b * 16384 + ch * 4096 + t] * mask[b * 4096 + t];
    } else if (idx < 262144 + 16384 + 262144 + 32) {
        out[OUT_ELEMS + (idx - 540672)] = 0.f;
    }
}

// -------------------------------------------------------------- fused0 ----
// (R2 — known good) Layer 0 fully fused, residual recomputed in epilogue.
// Register file is FULL during MFMA (64 AGPR acc + ~84 VGPR = 3 waves/SIMD);
// do NOT hold prefetched state across phase boundaries (R1/R3 spills).
__global__ __launch_bounds__(256, 3) void fused0_kernel(
    const float* __restrict__ x,
    ushort* __restrict__ hout, const ushort* __restrict__ wbf,
    const float* __restrict__ pre_w, const float* __restrict__ pre_b,
    const float* __restrict__ sep_w, const float* __restrict__ sep_b,
    const float* __restrict__ conv1_b,
    const float* __restrict__ n1g, const float* __restrict__ n1b,
    const float* __restrict__ n2g, const float* __restrict__ n2b,
    const float* __restrict__ mask)
{
    __shared__ __align__(16) ushort ylds[64 * 264];
    __shared__ float ssum[64][2];
    __shared__ float ssq[64][2];

    const int tid = threadIdx.x;
    const int lane = tid & 63;
    const int wv = tid >> 6;
    const int P = blockIdx.x;
    const int L = (P & 7) * 256 + (P >> 3);
    const int b = L >> 6;
    const int t0 = (L & 63) << 6;
    const float* maskb = mask + b * T_LEN;
    const float* xb0 = x + b * 16384;
    const float* xb1 = x + b * 16384 + 4096;
    const size_t hbase = (size_t)b * T_LEN * HC;

    // ---- phase 1: h from x + dwconv(1) + LN(n1) + gelu -> ylds ----
    {
        const int half = lane >> 5;
        const int ln32 = lane & 31;
        const int c0 = ln32 * 8;
        float w0[8], w1[8];
        #pragma unroll
        for (int j = 0; j < 4; ++j) {
            float4 wv4 = *(const float4*)(pre_w + c0 * 2 + 4 * j);
            w0[2 * j] = wv4.x; w1[2 * j] = wv4.y;
            w0[2 * j + 1] = wv4.z; w1[2 * j + 1] = wv4.w;
        }
        float pbv[8];
        *(float4*)(pbv + 0) = *(const float4*)(pre_b + c0);
        *(float4*)(pbv + 4) = *(const float4*)(pre_b + c0 + 4);
        float sw[24];
        #pragma unroll
        for (int j = 0; j < 6; ++j)
            *(float4*)(sw + 4 * j) = *(const float4*)(sep_w + c0 * 3 + 4 * j);
        float sbv[8], g1v[8], b1v[8];
        *(float4*)(sbv + 0) = *(const float4*)(sep_b + c0);
        *(float4*)(sbv + 4) = *(const float4*)(sep_b + c0 + 4);
        *(float4*)(g1v + 0) = *(const float4*)(n1g + c0);
        *(float4*)(g1v + 4) = *(const float4*)(n1g + c0 + 4);
        *(float4*)(b1v + 0) = *(const float4*)(n1b + c0);
        *(float4*)(b1v + 4) = *(const float4*)(n1b + c0 + 4);

        for (int mm = 0; mm < 8; ++mm) {
            const int rloc = wv * 16 + mm * 2 + half;
            const int t = t0 + rloc;
            const float xa = xb0[t], xc = xb1[t];
            const float mc = maskb[t];
            float xam = 0.f, xcm = 0.f, mmk = 0.f;
            float xap = 0.f, xcp = 0.f, mpk = 0.f;
            if (t >= 1) { xam = xb0[t - 1]; xcm = xb1[t - 1]; mmk = maskb[t - 1]; }
            if (t + 1 < T_LEN) { xap = xb0[t + 1]; xcp = xb1[t + 1]; mpk = maskb[t + 1]; }

            float v[8];
            float s = 0.f, q = 0.f;
            #pragma unroll
            for (int j = 0; j < 8; ++j) {
                const float hcj = fmaf(w0[j], xa, fmaf(w1[j], xc, pbv[j]));
                const float hmj = fmaf(w0[j], xam, fmaf(w1[j], xcm, pbv[j])) * mmk;
                const float hpj = fmaf(w0[j], xap, fmaf(w1[j], xcp, pbv[j])) * mpk;
                const float vv = sw[3 * j] * hmj + sw[3 * j + 1] * (hcj * mc)
                               + sw[3 * j + 2] * hpj + sbv[j];
                v[j] = vv;
                s += vv;
                q += vv * vv;
            }
            #pragma unroll
            for (int d = 16; d > 0; d >>= 1) {
                s += __shfl_xor(s, d, 64);
                q += __shfl_xor(q, d, 64);
            }
            const float mean = s * (1.f / 256.f);
            const float var = q * (1.f / 256.f) - mean * mean;
            const float rs = rsqrtf(var + 1e-5f);
            uint pk[4];
            #pragma unroll
            for (int j = 0; j < 4; ++j) {
                const float ya = gelu_f((v[2 * j] - mean) * rs * g1v[2 * j] + b1v[2 * j]);
                const float yb = gelu_f((v[2 * j + 1] - mean) * rs * g1v[2 * j + 1] + b1v[2 * j + 1]);
                pk[j] = (uint)f2bf(ya) | ((uint)f2bf(yb) << 16);
            }
            *(uint4*)(&ylds[rloc * 264 + c0]) = make_uint4(pk[0], pk[1], pk[2], pk[3]);
        }
    }
    __syncthreads();

    // ---- phase 2: pipelined MFMA, A from LDS ----
    const int lw = lane & 15;
    const int quad = lane >> 4;
    const int mh = wv >> 1;
    const int nh = wv & 1;
    floatx4 acc[2][8];
    #pragma unroll
    for (int m = 0; m < 2; ++m)
        #pragma unroll
        for (int n = 0; n < 8; ++n) acc[m][n] = (floatx4){0.f, 0.f, 0.f, 0.f};

    const ushort* wb = wbf + (nh * 128 + lw) * 256 + quad * 8;
    const ushort* la0 = &ylds[(mh * 32 + lw) * 264 + quad * 8];
    const ushort* la1 = &ylds[(mh * 32 + 16 + lw) * 264 + quad * 8];

    short8 a0c = *(const short8*)(la0);
    short8 a1c = *(const short8*)(la1);
    short8 bcur[8], bnx[8];
    #pragma unroll
    for (int n = 0; n < 8; ++n)
        bcur[n] = *(const short8*)(wb + n * 4096);

    short8 a0n, a1n;
    #pragma unroll
    for (int kt = 0; kt < 8; ++kt) {
        if (kt < 7) {
            a0n = *(const short8*)(la0 + (kt + 1) * 32);
            a1n = *(const short8*)(la1 + (kt + 1) * 32);
            #pragma unroll
            for (int n = 0; n < 8; ++n)
                bnx[n] = *(const short8*)(wb + n * 4096 + (kt + 1) * 32);
        }
        #pragma unroll
        for (int n = 0; n < 8; ++n) {
            acc[0][n] = __builtin_amdgcn_mfma_f32_16x16x32_bf16(a0c, bcur[n], acc[0][n], 0, 0, 0);
            acc[1][n] = __builtin_amdgcn_mfma_f32_16x16x32_bf16(a1c, bcur[n], acc[1][n], 0, 0, 0);
        }
        a0c = a0n;
        a1c = a1n;
        #pragma unroll
        for (int n = 0; n < 8; ++n) bcur[n] = bnx[n];
    }

    float sum[2][4] = {{0, 0, 0, 0}, {0, 0, 0, 0}};
    float sq[2][4] = {{0, 0, 0, 0}, {0, 0, 0, 0}};
    #pragma unroll
    for (int n = 0; n < 8; ++n) {
        const float cb = conv1_b[nh * 128 + n * 16 + lw];
        #pragma unroll
        for (int m = 0; m < 2; ++m)
            #pragma unroll
            for (int r = 0; r < 4; ++r) {
                const float val = acc[m][n][r] + cb;
                acc[m][n][r] = val;
                sum[m][r] += val;
                sq[m][r] += val * val;
            }
    }
    #pragma unroll
    for (int d = 1; d < 16; d <<= 1) {
        #pragma unroll
        for (int m = 0; m < 2; ++m)
            #pragma unroll
            for (int r = 0; r < 4; ++r) {
                sum[m][r] += __shfl_xor(sum[m][r], d, 64);
                sq[m][r] += __shfl_xor(sq[m][r], d, 64);
            }
    }
    if (lw == 0) {
        #pragma unroll
        for (int m = 0; m < 2; ++m)
            #pragma unroll
            for (int r = 0; r < 4; ++r) {
                ssum[mh * 32 + m * 16 + quad * 4 + r][nh] = sum[m][r];
                ssq[mh * 32 + m * 16 + quad * 4 + r][nh] = sq[m][r];
            }
    }
    __syncthreads();

    float mean[2][4], rsv[2][4];
    #pragma unroll
    for (int m = 0; m < 2; ++m)
        #pragma unroll
        for (int r = 0; r < 4; ++r) {
            const int row = mh * 32 + m * 16 + quad * 4 + r;
            const float s = ssum[row][0] + ssum[row][1];
            const float q = ssq[row][0] + ssq[row][1];
            mean[m][r] = s * (1.f / 256.f);
            const float var = q * (1.f / 256.f) - mean[m][r] * mean[m][r];
            rsv[m][r] = rsqrtf(var + 1e-5f);
        }
    #pragma unroll
    for (int n = 0; n < 8; ++n) {
        const int o = nh * 128 + n * 16 + lw;
        const float g2 = n2g[o], b2 = n2b[o];
        #pragma unroll
        for (int m = 0; m < 2; ++m)
            #pragma unroll
            for (int r = 0; r < 4; ++r) {
                const int row = mh * 32 + m * 16 + quad * 4 + r;
                const float y = gelu_f((acc[m][n][r] - mean[m][r]) * rsv[m][r] * g2 + b2);
                ylds[row * 264 + o] = f2bf(y);
            }
    }
    __syncthreads();

    // ---- epilogue: recompute residual h from x (bf16-rounded), add y ----
    {
        const int half = lane >> 5;
        const int ln32 = lane & 31;
        const int c0 = ln32 * 8;
        float w0[8], w1[8], pbv[8];
        #pragma unroll
        for (int j = 0; j < 4; ++j) {
            float4 wv4 = *(const float4*)(pre_w + c0 * 2 + 4 * j);
            w0[2 * j] = wv4.x; w1[2 * j] = wv4.y;
            w0[2 * j + 1] = wv4.z; w1[2 * j + 1] = wv4.w;
        }
        *(float4*)(pbv + 0) = *(const float4*)(pre_b + c0);
        *(float4*)(pbv + 4) = *(const float4*)(pre_b + c0 + 4);
        #pragma unroll
        for (int mm = 0; mm < 8; ++mm) {
            const int rloc = wv * 16 + mm * 2 + half;
            const int t = t0 + rloc;
            const float xa = xb0[t], xc = xb1[t];
            const uint4 yv = *(const uint4*)(&ylds[rloc * 264 + c0]);
            uint ov[4];
            const uint yw[4] = {yv.x, yv.y, yv.z, yv.w};
            #pragma unroll
            for (int j = 0; j < 4; ++j) {
                const float ha = bf2f(f2bf(fmaf(w0[2 * j], xa, fmaf(w1[2 * j], xc, pbv[2 * j]))));
                const float hb = bf2f(f2bf(fmaf(w0[2 * j + 1], xa, fmaf(w1[2 * j + 1], xc, pbv[2 * j + 1]))));
                ov[j] = addbf2f(yw[j], ha, hb);
            }
            *(uint4*)(hout + hbase + (size_t)t * HC + c0) =
                make_uint4(ov[0], ov[1], ov[2], ov[3]);
        }
    }
}

// --------------------------------------------------------------- fused ----
// (R2 — known good) Layers 1-2: dwconv+LN+gelu -> ylds, pipelined MFMA,
// LN(n2)+gelu+residual -> hout. Ping-pong, never in-place.
__global__ __launch_bounds__(256, 3) void fused_kernel(
    const ushort* __restrict__ hin, ushort* __restrict__ hout,
    const ushort* __restrict__ wbf,
    const float* __restrict__ sep_w, const float* __restrict__ sep_b,
    const float* __restrict__ conv1_b,
    const float* __restrict__ n1g, const float* __restrict__ n1b,
    const float* __restrict__ n2g, const float* __restrict__ n2b,
    const float* __restrict__ mask, int dil)
{
    __shared__ __align__(16) ushort ylds[64 * 264];
    __shared__ float ssum[64][2];
    __shared__ float ssq[64][2];

    const int tid = threadIdx.x;
    const int lane = tid & 63;
    const int wv = tid >> 6;
    const int P = blockIdx.x;
    const int L = (P & 7) * 256 + (P >> 3);
    const int b = L >> 6;
    const int t0 = (L & 63) << 6;
    const float* maskb = mask + b * T_LEN;
    const size_t hbase = (size_t)b * T_LEN * HC;

    {
        const int half = lane >> 5;
        const int ln32 = lane & 31;
        const int c0 = ln32 * 8;
        float sw[24];
        #pragma unroll
        for (int j = 0; j < 6; ++j)
            *(float4*)(sw + 4 * j) = *(const float4*)(sep_w + c0 * 3 + 4 * j);
        float sbv[8], g1v[8], b1v[8];
        *(float4*)(sbv + 0) = *(const float4*)(sep_b + c0);
        *(float4*)(sbv + 4) = *(const float4*)(sep_b + c0 + 4);
        *(float4*)(g1v + 0) = *(const float4*)(n1g + c0);
        *(float4*)(g1v + 4) = *(const float4*)(n1g + c0 + 4);
        *(float4*)(b1v + 0) = *(const float4*)(n1b + c0);
        *(float4*)(b1v + 4) = *(const float4*)(n1b + c0 + 4);

        // issue all 8 center-tap loads upfront (MLP across mm iterations)
        uint4 hraw[8];
        #pragma unroll
        for (int mm = 0; mm < 8; ++mm) {
            const int t = t0 + wv * 16 + mm * 2 + half;
            hraw[mm] = *(const uint4*)(hin + hbase + (size_t)t * HC + c0);
        }

        for (int mm = 0; mm < 8; ++mm) {
            const int rloc = wv * 16 + mm * 2 + half;
            const int t = t0 + rloc;
            float hm[8] = {0, 0, 0, 0, 0, 0, 0, 0};
            float hp[8] = {0, 0, 0, 0, 0, 0, 0, 0};
            float hc[8];
            unpack8(hraw[mm], maskb[t], hc);
            if (t >= dil)
                load8bf(hin + hbase + (size_t)(t - dil) * HC + c0, maskb[t - dil], hm);
            if (t + dil < T_LEN)
                load8bf(hin + hbase + (size_t)(t + dil) * HC + c0, maskb[t + dil], hp);
            float v[8];
            float s = 0.f, q = 0.f;
            #pragma unroll
            for (int j = 0; j < 8; ++j) {
                const float vv = sw[3 * j] * hm[j] + sw[3 * j + 1] * hc[j]
                               + sw[3 * j + 2] * hp[j] + sbv[j];
                v[j] = vv;
                s += vv;
                q += vv * vv;
            }
            #pragma unroll
            for (int d = 16; d > 0; d >>= 1) {
                s += __shfl_xor(s, d, 64);
                q += __shfl_xor(q, d, 64);
            }
            const float mean = s * (1.f / 256.f);
            const float var = q * (1.f / 256.f) - mean * mean;
            const float rs = rsqrtf(var + 1e-5f);
            uint pk[4];
            #pragma unroll
            for (int j = 0; j < 4; ++j) {
                const float ya = gelu_f((v[2 * j] - mean) * rs * g1v[2 * j] + b1v[2 * j]);
                const float yb = gelu_f((v[2 * j + 1] - mean) * rs * g1v[2 * j + 1] + b1v[2 * j + 1]);
                pk[j] = (uint)f2bf(ya) | ((uint)f2bf(yb) << 16);
            }
            *(uint4*)(&ylds[rloc * 264 + c0]) = make_uint4(pk[0], pk[1], pk[2], pk[3]);
        }
    }
    __syncthreads();

    const int lw = lane & 15;
    const int quad = lane >> 4;
    const int mh = wv >> 1;
    const int nh = wv & 1;
    floatx4 acc[2][8];
    #pragma unroll
    for (int m = 0; m < 2; ++m)
        #pragma unroll
        for (int n = 0; n < 8; ++n) acc[m][n] = (floatx4){0.f, 0.f, 0.f, 0.f};

    const ushort* wb = wbf + (nh * 128 + lw) * 256 + quad * 8;
    const ushort* la0 = &ylds[(mh * 32 + lw) * 264 + quad * 8];
    const ushort* la1 = &ylds[(mh * 32 + 16 + lw) * 264 + quad * 8];

    short8 a0c = *(const short8*)(la0);
    short8 a1c = *(const short8*)(la1);
    short8 bcur[8], bnx[8];
    #pragma unroll
    for (int n = 0; n < 8; ++n)
        bcur[n] = *(const short8*)(wb + n * 4096);

    short8 a0n, a1n;
    #pragma unroll
    for (int kt = 0; kt < 8; ++kt) {
        if (kt < 7) {
            a0n = *(const short8*)(la0 + (kt + 1) * 32);
            a1n = *(const short8*)(la1 + (kt + 1) * 32);
            #pragma unroll
            for (int n = 0; n < 8; ++n)
                bnx[n] = *(const short8*)(wb + n * 4096 + (kt + 1) * 32);
        }
        #pragma unroll
        for (int n = 0; n < 8; ++n) {
            acc[0][n] = __builtin_amdgcn_mfma_f32_16x16x32_bf16(a0c, bcur[n], acc[0][n], 0, 0, 0);
            acc[1][n] = __builtin_amdgcn_mfma_f32_16x16x32_bf16(a1c, bcur[n], acc[1][n], 0, 0, 0);
        }
        a0c = a0n;
        a1c = a1n;
        #pragma unroll
        for (int n = 0; n < 8; ++n) bcur[n] = bnx[n];
    }

    uint4 hv[8];
    #pragma unroll
    for (int jj = 0; jj < 8; ++jj) {
        const int idx = jj * 256 + tid;
        const int row = idx >> 5, seg = idx & 31;
        hv[jj] = *(const uint4*)(hin + hbase + (size_t)(t0 + row) * HC + seg * 8);
    }

    float sum[2][4] = {{0, 0, 0, 0}, {0, 0, 0, 0}};
    float sq[2][4] = {{0, 0, 0, 0}, {0, 0, 0, 0}};
    #pragma unroll
    for (int n = 0; n < 8; ++n) {
        const float cb = conv1_b[nh * 128 + n * 16 + lw];
        #pragma unroll
        for (int m = 0; m < 2; ++m)
            #pragma unroll
            for (int r = 0; r < 4; ++r) {
                const float val = acc[m][n][r] + cb;
                acc[m][n][r] = val;
                sum[m][r] += val;
                sq[m][r] += val * val;
            }
    }
    #pragma unroll
    for (int d = 1; d < 16; d <<= 1) {
        #pragma unroll
        for (int m = 0; m < 2; ++m)
            #pragma unroll
            for (int r = 0; r < 4; ++r) {
                sum[m][r] += __shfl_xor(sum[m][r], d, 64);
                sq[m][r] += __shfl_xor(sq[m][r], d, 64);
            }
    }
    if (lw == 0) {
        #pragma unroll
        for (int m = 0; m < 2; ++m)
            #pragma unroll
            for (int r = 0; r < 4; ++r) {
                ssum[mh * 32 + m * 16 + quad * 4 + r][nh] = sum[m][r];
                ssq[mh * 32 + m * 16 + quad * 4 + r][nh] = sq[m][r];
            }
    }
    __syncthreads();

    float mean[2][4], rsv[2][4];
    #pragma unroll
    for (int m = 0; m < 2; ++m)
        #pragma unroll
        for (int r = 0; r < 4; ++r) {
            const int row = mh * 32 + m * 16 + quad * 4 + r;
            const float s = ssum[row][0] + ssum[row][1];
            const float q = ssq[row][0] + ssq[row][1];
            mean[m][r] = s * (1.f / 256.f);
            const float var = q * (1.f / 256.f) - mean[m][r] * mean[m][r];
            rsv[m][r] = rsqrtf(var + 1e-5f);
        }
    #pragma unroll
    for (int n = 0; n < 8; ++n) {
        const int o = nh * 128 + n * 16 + lw;
        const float g2 = n2g[o], b2 = n2b[o];
        #pragma unroll
        for (int m = 0; m < 2; ++m)
            #pragma unroll
            for (int r = 0; r < 4; ++r) {
                const int row = mh * 32 + m * 16 + quad * 4 + r;
                const float y = gelu_f((acc[m][n][r] - mean[m][r]) * rsv[m][r] * g2 + b2);
                ylds[row * 264 + o] = f2bf(y);
            }
    }
    __syncthreads();

    #pragma unroll
    for (int jj = 0; jj < 8; ++jj) {
        const int idx = jj * 256 + tid;
        const int row = idx >> 5, seg = idx & 31;
        const size_t g = hbase + (size_t)(t0 + row) * HC + seg * 8;
        const uint4 yv = *(const uint4*)(&ylds[row * 264 + seg * 8]);
        uint4 ov;
        ov.x = addbf2(yv.x, hv[jj].x);
        ov.y = addbf2(yv.y, hv[jj].y);
        ov.z = addbf2(yv.z, hv[jj].z);
        ov.w = addbf2(yv.w, hv[jj].w);
        *(uint4*)(hout + g) = ov;
    }
}

// ---------------------------------------------------------- fused+proj ----
// Layer 3 (dil=27) + proj + spline, fully fused. h3 is NOT an output and
// its only consumer was proj — so the residual add writes h3 back into
// ylds IN PLACE (per-thread same-address, no hazard) instead of global,
// then proj's MFMA reads A-fragments from ylds (identical stride-264
// addressing as the old proj alds). Deletes the 67MB h3 write + 67MB proj
// read + one dispatch. slds/exch alias ylds after a barrier (22.3KB<33.8KB).
__global__ __launch_bounds__(256, 3) void fused_proj_kernel(
    const ushort* __restrict__ hin,
    const ushort* __restrict__ wbf, const ushort* __restrict__ pwbf,
    const float* __restrict__ sep_w, const float* __restrict__ sep_b,
    const float* __restrict__ conv1_b,
    const float* __restrict__ n1g, const float* __restrict__ n1b,
    const float* __restrict__ n2g, const float* __restrict__ n2b,
    const float* __restrict__ projb, const float* __restrict__ x,
    const float* __restrict__ mask, float* __restrict__ out, int dil)
{
    __shared__ __align__(16) ushort ylds[64 * 264];
    __shared__ float ssum[64][2];
    __shared__ float ssq[64][2];
    __shared__ float red[4];

    const int tid = threadIdx.x;
    const int lane = tid & 63;
    const int wv = tid >> 6;
    const int P = blockIdx.x;
    const int L = (P & 7) * 256 + (P >> 3);
    const int b = L >> 6;
    const int t0 = (L & 63) << 6;
    const float* maskb = mask + b * T_LEN;
    const size_t hbase = (size_t)b * T_LEN * HC;

    // ---- phase 1: dwconv(dil)+LN(n1)+gelu -> ylds (verbatim fused) ----
    {
        const int half = lane >> 5;
        const int ln32 = lane & 31;
        const int c0 = ln32 * 8;
        float sw[24];
        #pragma unroll
        for (int j = 0; j < 6; ++j)
            *(float4*)(sw + 4 * j) = *(const float4*)(sep_w + c0 * 3 + 4 * j);
        float sbv[8], g1v[8], b1v[8];
        *(float4*)(sbv + 0) = *(const float4*)(sep_b + c0);
        *(float4*)(sbv + 4) = *(const float4*)(sep_b + c0 + 4);
        *(float4*)(g1v + 0) = *(const float4*)(n1g + c0);
        *(float4*)(g1v + 4) = *(const float4*)(n1g + c0 + 4);
        *(float4*)(b1v + 0) = *(const float4*)(n1b + c0);
        *(float4*)(b1v + 4) = *(const float4*)(n1b + c0 + 4);

        uint4 hraw[8];
        #pragma unroll
        for (int mm = 0; mm < 8; ++mm) {
            const int t = t0 + wv * 16 + mm * 2 + half;
            hraw[mm] = *(const uint4*)(hin + hbase + (size_t)t * HC + c0);
        }

        for (int mm = 0; mm < 8; ++mm) {
            const int rloc = wv * 16 + mm * 2 + half;
            const int t = t0 + rloc;
            float hm[8] = {0, 0, 0, 0, 0, 0, 0, 0};
            float hp[8] = {0, 0, 0, 0, 0, 0, 0, 0};
            float hc[8];
            unpack8(hraw[mm], maskb[t], hc);
            if (t >= dil)
                load8bf(hin + hbase + (size_t)(t - dil) * HC + c0, maskb[t - dil], hm);
            if (t + dil < T_LEN)
                load8bf(hin + hbase + (size_t)(t + dil) * HC + c0, maskb[t + dil], hp);
            float v[8];
            float s = 0.f, q = 0.f;
            #pragma unroll
            for (int j = 0; j < 8; ++j) {
                const float vv = sw[3 * j] * hm[j] + sw[3 * j + 1] * hc[j]
                               + sw[3 * j + 2] * hp[j] + sbv[j];
                v[j] = vv;
                s += vv;
                q += vv * vv;
            }
            #pragma unroll
            for (int d = 16; d > 0; d >>= 1) {
                s += __shfl_xor(s, d, 64);
                q += __shfl_xor(q, d, 64);
            }
            const float mean = s * (1.f / 256.f);
            const float var = q * (1.f / 256.f) - mean * mean;
            const float rs = rsqrtf(var + 1e-5f);
            uint pk[4];
            #pragma unroll
            for (int j = 0; j < 4; ++j) {
                const float ya = gelu_f((v[2 * j] - mean) * rs * g1v[2 * j] + b1v[2 * j]);
                const float yb = gelu_f((v[2 * j + 1] - mean) * rs * g1v[2 * j + 1] + b1v[2 * j + 1]);
                pk[j] = (uint)f2bf(ya) | ((uint)f2bf(yb) << 16);
            }
            *(uint4*)(&ylds[rloc * 264 + c0]) = make_uint4(pk[0], pk[1], pk[2], pk[3]);
        }
    }
    __syncthreads();

    // ---- phase 2: conv1 MFMA (verbatim fused) ----
    const int lw = lane & 15;
    const int quad = lane >> 4;
    const int mh = wv >> 1;
    const int nh = wv & 1;
    floatx4 acc[2][8];
    #pragma unroll
    for (int m = 0; m < 2; ++m)
        #pragma unroll
        for (int n = 0; n < 8; ++n) acc[m][n] = (floatx4){0.f, 0.f, 0.f, 0.f};

    const ushort* wb = wbf + (nh * 128 + lw) * 256 + quad * 8;
    const ushort* la0 = &ylds[(mh * 32 + lw) * 264 + quad * 8];
    const ushort* la1 = &ylds[(mh * 32 + 16 + lw) * 264 + quad * 8];

    short8 a0c = *(const short8*)(la0);
    short8 a1c = *(const short8*)(la1);
    short8 bcur[8], bnx[8];
    #pragma unroll
    for (int n = 0; n < 8; ++n)
        bcur[n] = *(const short8*)(wb + n * 4096);

    short8 a0n, a1n;
    #pragma unroll
    for (int kt = 0; kt < 8; ++kt) {
        if (kt < 7) {
            a0n = *(const short8*)(la0 + (kt + 1) * 32);
            a1n = *(const short8*)(la1 + (kt + 1) * 32);
            #pragma unroll
            for (int n = 0; n < 8; ++n)
                bnx[n] = *(const short8*)(wb + n * 4096 + (kt + 1) * 32);
        }
        #pragma unroll
        for (int n = 0; n < 8; ++n) {
            acc[0][n] = __builtin_amdgcn_mfma_f32_16x16x32_bf16(a0c, bcur[n], acc[0][n], 0, 0, 0);
            acc[1][n] = __builtin_amdgcn_mfma_f32_16x16x32_bf16(a1c, bcur[n], acc[1][n], 0, 0, 0);
        }
        a0c = a0n;
        a1c = a1n;
        #pragma unroll
        for (int n = 0; n < 8; ++n) bcur[n] = bnx[n];
    }

    uint4 hv[8];
    #pragma unroll
    for (int jj = 0; jj < 8; ++jj) {
        const int idx = jj * 256 + tid;
        const int row = idx >> 5, seg = idx & 31;
        hv[jj] = *(const uint4*)(hin + hbase + (size_t)(t0 + row) * HC + seg * 8);
    }

    float sum[2][4] = {{0, 0, 0, 0}, {0, 0, 0, 0}};
    float sq[2][4] = {{0, 0, 0, 0}, {0, 0, 0, 0}};
    #pragma unroll
    for (int n = 0; n < 8; ++n) {
        const float cb = conv1_b[nh * 128 + n * 16 + lw];
        #pragma unroll
        for (int m = 0; m < 2; ++m)
            #pragma unroll
            for (int r = 0; r < 4; ++r) {
                const float val = acc[m][n][r] + cb;
                acc[m][n][r] = val;
                sum[m][r] += val;
                sq[m][r] += val * val;
            }
    }
    #pragma unroll
    for (int d = 1; d < 16; d <<= 1) {
        #pragma unroll
        for (int m = 0; m < 2; ++m)
            #pragma unroll
            for (int r = 0; r < 4; ++r) {
                sum[m][r] += __shfl_xor(sum[m][r], d, 64);
                sq[m][r] += __shfl_xor(sq[m][r], d, 64);
            }
    }
    if (lw == 0) {
        #pragma unroll
        for (int m = 0; m < 2; ++m)
            #pragma unroll
            for (int r = 0; r < 4; ++r) {
                ssum[mh * 32 + m * 16 + quad * 4 + r][nh] = sum[m][r];
                ssq[mh * 32 + m * 16 + quad * 4 + r][nh] = sq[m][r];
            }
    }
    __syncthreads();

    float mean[2][4], rsv[2][4];
    #pragma unroll
    for (int m = 0; m < 2; ++m)
        #pragma unroll
        for (int r = 0; r < 4; ++r) {
            const int row = mh * 32 + m * 16 + quad * 4 + r;
            const float s = ssum[row][0] + ssum[row][1];
            const float q = ssq[row][0] + ssq[row][1];
            mean[m][r] = s * (1.f / 256.f);
            const float var = q * (1.f / 256.f) - mean[m][r] * mean[m][r];
            rsv[m][r] = rsqrtf(var + 1e-5f);
        }
    #pragma unroll
    for (int n = 0; n < 8; ++n) {
        const int o = nh * 128 + n * 16 + lw;
        const float g2 = n2g[o], b2 = n2b[o];
        #pragma unroll
        for (int m = 0; m < 2; ++m)
            #pragma unroll
            for (int r = 0; r < 4; ++r) {
                const int row = mh * 32 + m * 16 + quad * 4 + r;
                const float y = gelu_f((acc[m][n][r] - mean[m][r]) * rsv[m][r] * g2 + b2);
                ylds[row * 264 + o] = f2bf(y);
            }
    }
    __syncthreads();

    // ---- residual add IN PLACE: ylds <- h3 = y + h (no global write) ----
    #pragma unroll
    for (int jj = 0; jj < 8; ++jj) {
        const int idx = jj * 256 + tid;
        const int row = idx >> 5, seg = idx & 31;
        uint4 yv = *(const uint4*)(&ylds[row * 264 + seg * 8]);
        uint4 ov;
        ov.x = addbf2(yv.x, hv[jj].x);
        ov.y = addbf2(yv.y, hv[jj].y);
        ov.z = addbf2(yv.z, hv[jj].z);
        ov.w = addbf2(yv.w, hv[jj].w);
        *(uint4*)(&ylds[row * 264 + seg * 8]) = ov;
    }
    __syncthreads();

    // ---- proj MFMA: A = h3 from ylds (same addressing as old proj) ----
    floatx4 acc2[4];
    #pragma unroll
    for (int n = 0; n < 4; ++n) acc2[n] = (floatx4){0.f, 0.f, 0.f, 0.f};
    #pragma unroll
    for (int kt = 0; kt < 8; ++kt) {
        short8 a = *(short8*)(&ylds[(wv * 16 + lw) * 264 + kt * 32 + quad * 8]);
        #pragma unroll
        for (int n = 0; n < 4; ++n) {
            short8 bb = *(const short8*)(pwbf + (n * 16 + lw) * 256 + kt * 32 + quad * 8);
            acc2[n] = __builtin_amdgcn_mfma_f32_16x16x32_bf16(a, bb, acc2[n], 0, 0, 0);
        }
    }
    __syncthreads();   // all ylds reads done -> safe to alias as slds/exch

    float* slds = reinterpret_cast<float*>(ylds);           // 64 x 65 floats
    float* exch = reinterpret_cast<float*>(ylds) + 64 * 65; // 128 x 11 floats
    #pragma unroll
    for (int n = 0; n < 4; ++n) {
        const int o = n * 16 + lw;
        const float pb = (o < 58) ? projb[o] : 0.f;
        #pragma unroll
        for (int r = 0; r < 4; ++r) {
            const int row = wv * 16 + quad * 4 + r;
            const float mv = maskb[t0 + row];
            slds[row * 65 + o] = acc2[n][r] * mv + pb;
        }
    }
    __syncthreads();

    // ---- spline (A/B pair-split, verbatim R4) ----
    const int item = tid & 127;
    const int pos = item >> 1;
    const int ch = item & 1;
    const int t = t0 + pos;
    const bool isA = tid < 128;
    const float SC = 0.0625f;

    float cwv[11], wdv[10], chv[11], htv[10];
    float x1 = 0.f, mv = 0.f;

    if (!isA) {
        #pragma unroll
        for (int j = 1; j <= 9; ++j) {
            const float u = slds[pos * 65 + ch * 29 + 19 + j];
            exch[item * 11 + (j - 1)] = 0.001f + softplus_f(u);
        }
    } else {
        x1 = x[b * 16384 + (2 + ch) * 4096 + t];
        mv = maskb[t];
        float svA[20];
        #pragma unroll
        for (int j = 0; j < 20; ++j) svA[j] = slds[pos * 65 + ch * 29 + j];
        {
            float u[10];
            float mx = -1e30f;
            #pragma unroll
            for (int j = 0; j < 10; ++j) { u[j] = svA[j] * SC; mx = fmaxf(mx, u[j]); }
            float ssm = 0.f;
            #pragma unroll
            for (int j = 0; j < 10; ++j) { u[j] = expf(u[j] - mx); ssm += u[j]; }
            const float inv = 1.f / ssm;
            float cum = 0.f;
            cwv[0] = -5.f;
            #pragma unroll
            for (int j = 0; j < 10; ++j) {
                cum += 0.001f + 0.99f * u[j] * inv;
                cwv[j + 1] = 10.f * cum - 5.f;
            }
            cwv[10] = 5.f;
            #pragma unroll
            for (int j = 0; j < 10; ++j) wdv[j] = cwv[j + 1] - cwv[j];
        }
        {
            float u[10];
            float mx = -1e30f;
            #pragma unroll
            for (int j = 0; j < 10; ++j) { u[j] = svA[10 + j] * SC; mx = fmaxf(mx, u[j]); }
            float ssm = 0.f;
            #pragma unroll
            for (int j = 0; j < 10; ++j) { u[j] = expf(u[j] - mx); ssm += u[j]; }
            const float inv = 1.f / ssm;
            float cum = 0.f;
            chv[0] = -5.f;
            #pragma unroll
            for (int j = 0; j < 10; ++j) {
                cum += 0.001f + 0.99f * u[j] * inv;
                chv[j + 1] = 10.f * cum - 5.f;
            }
            chv[10] = 5.f;
            #pragma unroll
            for (int j = 0; j < 10; ++j) htv[j] = chv[j + 1] - chv[j];
        }
    }
    __syncthreads();   // B's exch visible to A

    float contrib = 0.f;
    if (isA) {
        float dvv[11];
        dvv[0] = 1.f;
        dvv[10] = 1.f;
        #pragma unroll
        for (int j = 1; j <= 9; ++j) dvv[j] = exch[item * 11 + (j - 1)];

        const bool inside = (x1 >= -5.f) && (x1 <= 5.f);
        const float xc = fminf(fmaxf(x1, -5.f), 5.f);
        float in_cw = cwv[0], in_w = wdv[0], in_ch = chv[0], in_h = htv[0];
        float dk = dvv[0], dk1 = dvv[1];
        #pragma unroll
        for (int j = 1; j < 10; ++j) {
            const bool ge = (xc >= cwv[j]);
            in_cw = ge ? cwv[j] : in_cw;
            in_w  = ge ? wdv[j] : in_w;
            in_ch = ge ? chv[j] : in_ch;
            in_h  = ge ? htv[j] : in_h;
            dk    = ge ? dvv[j] : dk;
            dk1   = ge ? dvv[j + 1] : dk1;
        }
        const float th = (xc - in_cw) / in_w;
        const float t1m = th * (1.f - th);
        const float dl = in_h / in_w;
        const float num = in_h * (dl * th * th + dk * t1m);
        const float den = dl + (dk + dk1 - 2.f * dl) * t1m;
        float yv = in_ch + num / den;
        const float omt = 1.f - th;
        const float dnum = dl * dl * (dk1 * th * th + 2.f * dl * t1m + dk * omt * omt);
        float lad = logf(dnum) - 2.f * logf(den);
        if (!inside) { yv = x1; lad = 0.f; }
        out[b * 16384 + (2 + ch) * 4096 + t] = yv * mv;
        contrib = lad * mv;
    }
    #pragma unroll
    for (int d = 32; d > 0; d >>= 1) contrib += __shfl_xor(contrib, d, 64);
    if (lane == 0) red[wv] = contrib;
    __syncthreads();
    if (tid == 0) atomicAdd(out + OUT_ELEMS + b, red[0] + red[1] + red[2] + red[3]);
}

// -------------------------------------------------------------- launch ----
extern "C" void kernel_launch(void* const* d_in, const int* in_sizes, int n_in,
                              void* d_out, int out_size, void* d_ws, size_t ws_size,
                              hipStream_t stream) {
    const float* x      = (const float*)d_in[0];
    const float* mask   = (const float*)d_in[1];
    const float* pre_w  = (const float*)d_in[2];
    const float* pre_b  = (const float*)d_in[3];
    const float* sep_w  = (const float*)d_in[4];
    const float* sep_b  = (const float*)d_in[5];
    const float* conv1w = (const float*)d_in[6];
    const float* conv1b = (const float*)d_in[7];
    const float* n1g    = (const float*)d_in[8];
    const float* n1b    = (const float*)d_in[9];
    const float* n2g    = (const float*)d_in[10];
    const float* n2b    = (const float*)d_in[11];
    const float* projw  = (const float*)d_in[12];
    const float* projb  = (const float*)d_in[13];
    float* out = (float*)d_out;

    ushort* h0   = (ushort*)d_ws;
    ushort* h1   = h0 + (size_t)NPOS * HC;
    ushort* wbf  = h1 + (size_t)NPOS * HC;
    ushort* pwbf = wbf + 4 * 256 * 256;

    prep_kernel<<<2113, 256, 0, stream>>>(conv1w, projw, x, mask, wbf, pwbf, out);

    // layer 0: fully fused, residual recomputed in epilogue (no hg stream)
    fused0_kernel<<<2048, 256, 0, stream>>>(x, h1, wbf,
        pre_w, pre_b, sep_w, sep_b, conv1b, n1g, n1b, n2g, n2b, mask);

    // layers 1-2: fully fused; ping-pong, never in-place
    fused_kernel<<<2048, 256, 0, stream>>>(h1, h0, wbf + 1 * 65536,
        sep_w + 1 * 768, sep_b + 1 * 256, conv1b + 1 * 256,
        n1g + 1 * 256, n1b + 1 * 256, n2g + 1 * 256, n2b + 1 * 256, mask, 3);
    fused_kernel<<<2048, 256, 0, stream>>>(h0, h1, wbf + 2 * 65536,
        sep_w + 2 * 768, sep_b + 2 * 256, conv1b + 2 * 256,
        n1g + 2 * 256, n1b + 2 * 256, n2g + 2 * 256, n2b + 2 * 256, mask, 9);

    // layer 3 + proj + spline fused: h3 never touches global memory
    fused_proj_kernel<<<2048, 256, 0, stream>>>(h1, wbf + 3 * 65536, pwbf,
        sep_w + 3 * 768, sep_b + 3 * 256, conv1b + 3 * 256,
        n1g + 3 * 256, n1b + 3 * 256, n2g + 3 * 256, n2b + 3 * 256,
        projb, x, mask, out, 27);
}

// Round 6
// 504.233 us; speedup vs baseline: 1.2260x; 1.0403x over previous
//
#include <hip/hip_runtime.h>
#include <cmath>

typedef short short8 __attribute__((ext_vector_type(8)));
typedef float floatx4 __attribute__((ext_vector_type(4)));
typedef float floatx2 __attribute__((ext_vector_type(2)));

#define T_LEN 4096
#define HC 256
#define NPOS (32 * 4096)
#define OUT_ELEMS (32 * 4 * 4096)

__device__ __forceinline__ ushort f2bf(float f) {
    uint u = __float_as_uint(f);
    u += 0x7FFFu + ((u >> 16) & 1u);
    return (ushort)(u >> 16);
}
__device__ __forceinline__ float bf2f(ushort u) {
    return __uint_as_float(((uint)u) << 16);
}
__device__ __forceinline__ uint addbf2(uint a, uint b) {
    const float lo = bf2f((ushort)(a & 0xffffu)) + bf2f((ushort)(b & 0xffffu));
    const float hi = bf2f((ushort)(a >> 16)) + bf2f((ushort)(b >> 16));
    return (uint)f2bf(lo) | ((uint)f2bf(hi) << 16);
}
__device__ __forceinline__ uint addbf2f(uint y, float ha, float hb) {
    const float lo = bf2f((ushort)(y & 0xffffu)) + ha;
    const float hi = bf2f((ushort)(y >> 16)) + hb;
    return (uint)f2bf(lo) | ((uint)f2bf(hi) << 16);
}
// unpack a bf16 pair word into floatx2 {lo, hi} — 2 bit-ops, no shifts needed for hi
__device__ __forceinline__ floatx2 bf2x2(uint u) {
    floatx2 t;
    t[0] = __uint_as_float(u << 16);
    t[1] = __uint_as_float(u & 0xffff0000u);
    return t;
}
// fast tanh-form gelu; scalar and packed-pair variants (pk_fma for the poly part)
__device__ __forceinline__ float gelu_f(float x) {
    const float x2 = x * x;
    const float w = fmaf(0.044715f * x2, x, x);
    const float e = __builtin_amdgcn_exp2f(2.3022084f * w);
    const float r = __builtin_amdgcn_rcpf(1.f + e);
    return fmaf(-x, r, x);
}
__device__ __forceinline__ floatx2 gelu2(floatx2 x) {
    const floatx2 x2 = x * x;
    const floatx2 w = 0.044715f * x2 * x + x;
    floatx2 e, r;
    e[0] = __builtin_amdgcn_exp2f(2.3022084f * w[0]);
    e[1] = __builtin_amdgcn_exp2f(2.3022084f * w[1]);
    r[0] = __builtin_amdgcn_rcpf(1.f + e[0]);
    r[1] = __builtin_amdgcn_rcpf(1.f + e[1]);
    return x - x * r;
}
__device__ __forceinline__ float softplus_f(float x) {
    return (x > 20.f) ? x : log1pf(expf(x));
}

// ---------------------------------------------------------------- prep ----
__global__ __launch_bounds__(256) void prep_kernel(
    const float* __restrict__ cw, const float* __restrict__ pw,
    const float* __restrict__ x, const float* __restrict__ mask,
    ushort* __restrict__ wbf, ushort* __restrict__ pwbf,
    float* __restrict__ out)
{
    int idx = blockIdx.x * 256 + threadIdx.x;
    if (idx < 262144) {
        wbf[idx] = f2bf(cw[idx]);
    } else if (idx < 262144 + 16384) {
        int j = idx - 262144;
        int row = j >> 8, c = j & 255;
        pwbf[j] = (row < 58) ? f2bf(pw[row * 256 + c]) : (ushort)0;
    } else if (idx < 262144 + 16384 + 262144) {
        int j = idx - 278528;
        int b = j >> 13;
        int r = j & 8191;
        int ch = r >> 12;
        int t = r & 4095;
        out[b * 16384 + ch * 4096 + t] =
            x[b * 16384 + ch * 4096 + t] * mask[b * 4096 + t];
    } else if (idx < 262144 + 16384 + 262144 + 32) {
        out[OUT_ELEMS + (idx - 540672)] = 0.f;
    }
}

// -------------------------------------------------------------- fused0 ----
// (R5 structure) Layer 0 fully fused, residual recomputed in epilogue.
// R6: phase-1 / epilogue math rewritten in floatx2 so hipcc emits packed
// v_pk_fma_f32 (2 FLOP/lane/inst). Same IEEE ops, structure unchanged.
// Register file FULL during MFMA — no state may live across phases (R1/R3).
__global__ __launch_bounds__(256, 3) void fused0_kernel(
    const float* __restrict__ x,
    ushort* __restrict__ hout, const ushort* __restrict__ wbf,
    const float* __restrict__ pre_w, const float* __restrict__ pre_b,
    const float* __restrict__ sep_w, const float* __restrict__ sep_b,
    const float* __restrict__ conv1_b,
    const float* __restrict__ n1g, const float* __restrict__ n1b,
    const float* __restrict__ n2g, const float* __restrict__ n2b,
    const float* __restrict__ mask)
{
    __shared__ __align__(16) ushort ylds[64 * 264];
    __shared__ float ssum[64][2];
    __shared__ float ssq[64][2];

    const int tid = threadIdx.x;
    const int lane = tid & 63;
    const int wv = tid >> 6;
    const int P = blockIdx.x;
    const int L = (P & 7) * 256 + (P >> 3);
    const int b = L >> 6;
    const int t0 = (L & 63) << 6;
    const float* maskb = mask + b * T_LEN;
    const float* xb0 = x + b * 16384;
    const float* xb1 = x + b * 16384 + 4096;
    const size_t hbase = (size_t)b * T_LEN * HC;

    // ---- phase 1: h from x + dwconv(1) + LN(n1) + gelu -> ylds ----
    {
        const int half = lane >> 5;
        const int ln32 = lane & 31;
        const int c0 = ln32 * 8;
        floatx2 w0p[4], w1p[4], pbp[4];
        #pragma unroll
        for (int j = 0; j < 4; ++j) {
            float4 wv4 = *(const float4*)(pre_w + c0 * 2 + 4 * j);
            w0p[j] = (floatx2){wv4.x, wv4.z};
            w1p[j] = (floatx2){wv4.y, wv4.w};
        }
        float pbv[8];
        *(float4*)(pbv + 0) = *(const float4*)(pre_b + c0);
        *(float4*)(pbv + 4) = *(const float4*)(pre_b + c0 + 4);
        float sw[24];
        #pragma unroll
        for (int j = 0; j < 6; ++j)
            *(float4*)(sw + 4 * j) = *(const float4*)(sep_w + c0 * 3 + 4 * j);
        float sbv[8], g1v[8], b1v[8];
        *(float4*)(sbv + 0) = *(const float4*)(sep_b + c0);
        *(float4*)(sbv + 4) = *(const float4*)(sep_b + c0 + 4);
        *(float4*)(g1v + 0) = *(const float4*)(n1g + c0);
        *(float4*)(g1v + 4) = *(const float4*)(n1g + c0 + 4);
        *(float4*)(b1v + 0) = *(const float4*)(n1b + c0);
        *(float4*)(b1v + 4) = *(const float4*)(n1b + c0 + 4);
        floatx2 sw0p[4], sw1p[4], sw2p[4], sbp[4], g1p[4], b1p[4];
        #pragma unroll
        for (int p = 0; p < 4; ++p) {
            pbp[p]  = (floatx2){pbv[2 * p], pbv[2 * p + 1]};
            sw0p[p] = (floatx2){sw[6 * p],     sw[6 * p + 3]};
            sw1p[p] = (floatx2){sw[6 * p + 1], sw[6 * p + 4]};
            sw2p[p] = (floatx2){sw[6 * p + 2], sw[6 * p + 5]};
            sbp[p]  = (floatx2){sbv[2 * p], sbv[2 * p + 1]};
            g1p[p]  = (floatx2){g1v[2 * p], g1v[2 * p + 1]};
            b1p[p]  = (floatx2){b1v[2 * p], b1v[2 * p + 1]};
        }

        for (int mm = 0; mm < 8; ++mm) {
            const int rloc = wv * 16 + mm * 2 + half;
            const int t = t0 + rloc;
            const float xa = xb0[t], xc = xb1[t];
            const float mc = maskb[t];
            float xam = 0.f, xcm = 0.f, mmk = 0.f;
            float xap = 0.f, xcp = 0.f, mpk = 0.f;
            if (t >= 1) { xam = xb0[t - 1]; xcm = xb1[t - 1]; mmk = maskb[t - 1]; }
            if (t + 1 < T_LEN) { xap = xb0[t + 1]; xcp = xb1[t + 1]; mpk = maskb[t + 1]; }

            floatx2 v2[4];
            floatx2 s2 = (floatx2){0.f, 0.f}, q2 = (floatx2){0.f, 0.f};
            #pragma unroll
            for (int p = 0; p < 4; ++p) {
                const floatx2 hc2 = w0p[p] * xa + w1p[p] * xc + pbp[p];
                const floatx2 hm2 = (w0p[p] * xam + w1p[p] * xcm + pbp[p]) * mmk;
                const floatx2 hp2 = (w0p[p] * xap + w1p[p] * xcp + pbp[p]) * mpk;
                const floatx2 vv = sw0p[p] * hm2 + sw1p[p] * (hc2 * mc)
                                 + sw2p[p] * hp2 + sbp[p];
                v2[p] = vv;
                s2 += vv;
                q2 += vv * vv;
            }
            float s = s2[0] + s2[1], q = q2[0] + q2[1];
            #pragma unroll
            for (int d = 16; d > 0; d >>= 1) {
                s += __shfl_xor(s, d, 64);
                q += __shfl_xor(q, d, 64);
            }
            const float mean = s * (1.f / 256.f);
            const float var = q * (1.f / 256.f) - mean * mean;
            const float rs = rsqrtf(var + 1e-5f);
            uint pk[4];
            #pragma unroll
            for (int p = 0; p < 4; ++p) {
                const floatx2 y2 = gelu2((v2[p] - mean) * rs * g1p[p] + b1p[p]);
                pk[p] = (uint)f2bf(y2[0]) | ((uint)f2bf(y2[1]) << 16);
            }
            *(uint4*)(&ylds[rloc * 264 + c0]) = make_uint4(pk[0], pk[1], pk[2], pk[3]);
        }
    }
    __syncthreads();

    // ---- phase 2: pipelined MFMA, A from LDS ----
    const int lw = lane & 15;
    const int quad = lane >> 4;
    const int mh = wv >> 1;
    const int nh = wv & 1;
    floatx4 acc[2][8];
    #pragma unroll
    for (int m = 0; m < 2; ++m)
        #pragma unroll
        for (int n = 0; n < 8; ++n) acc[m][n] = (floatx4){0.f, 0.f, 0.f, 0.f};

    const ushort* wb = wbf + (nh * 128 + lw) * 256 + quad * 8;
    const ushort* la0 = &ylds[(mh * 32 + lw) * 264 + quad * 8];
    const ushort* la1 = &ylds[(mh * 32 + 16 + lw) * 264 + quad * 8];

    short8 a0c = *(const short8*)(la0);
    short8 a1c = *(const short8*)(la1);
    short8 bcur[8], bnx[8];
    #pragma unroll
    for (int n = 0; n < 8; ++n)
        bcur[n] = *(const short8*)(wb + n * 4096);

    short8 a0n, a1n;
    #pragma unroll
    for (int kt = 0; kt < 8; ++kt) {
        if (kt < 7) {
            a0n = *(const short8*)(la0 + (kt + 1) * 32);
            a1n = *(const short8*)(la1 + (kt + 1) * 32);
            #pragma unroll
            for (int n = 0; n < 8; ++n)
                bnx[n] = *(const short8*)(wb + n * 4096 + (kt + 1) * 32);
        }
        #pragma unroll
        for (int n = 0; n < 8; ++n) {
            acc[0][n] = __builtin_amdgcn_mfma_f32_16x16x32_bf16(a0c, bcur[n], acc[0][n], 0, 0, 0);
            acc[1][n] = __builtin_amdgcn_mfma_f32_16x16x32_bf16(a1c, bcur[n], acc[1][n], 0, 0, 0);
        }
        a0c = a0n;
        a1c = a1n;
        #pragma unroll
        for (int n = 0; n < 8; ++n) bcur[n] = bnx[n];
    }

    floatx4 sum4[2], sq4[2];
    #pragma unroll
    for (int m = 0; m < 2; ++m) {
        sum4[m] = (floatx4){0.f, 0.f, 0.f, 0.f};
        sq4[m] = (floatx4){0.f, 0.f, 0.f, 0.f};
    }
    #pragma unroll
    for (int n = 0; n < 8; ++n) {
        const float cb = conv1_b[nh * 128 + n * 16 + lw];
        #pragma unroll
        for (int m = 0; m < 2; ++m) {
            const floatx4 val = acc[m][n] + cb;
            acc[m][n] = val;
            sum4[m] += val;
            sq4[m] += val * val;
        }
    }
    #pragma unroll
    for (int d = 1; d < 16; d <<= 1) {
        #pragma unroll
        for (int m = 0; m < 2; ++m)
            #pragma unroll
            for (int r = 0; r < 4; ++r) {
                sum4[m][r] += __shfl_xor(sum4[m][r], d, 64);
                sq4[m][r] += __shfl_xor(sq4[m][r], d, 64);
            }
    }
    if (lw == 0) {
        #pragma unroll
        for (int m = 0; m < 2; ++m)
            #pragma unroll
            for (int r = 0; r < 4; ++r) {
                ssum[mh * 32 + m * 16 + quad * 4 + r][nh] = sum4[m][r];
                ssq[mh * 32 + m * 16 + quad * 4 + r][nh] = sq4[m][r];
            }
    }
    __syncthreads();

    float mean[2][4], rsv[2][4];
    #pragma unroll
    for (int m = 0; m < 2; ++m)
        #pragma unroll
        for (int r = 0; r < 4; ++r) {
            const int row = mh * 32 + m * 16 + quad * 4 + r;
            const float s = ssum[row][0] + ssum[row][1];
            const float q = ssq[row][0] + ssq[row][1];
            mean[m][r] = s * (1.f / 256.f);
            const float var = q * (1.f / 256.f) - mean[m][r] * mean[m][r];
            rsv[m][r] = rsqrtf(var + 1e-5f);
        }
    #pragma unroll
    for (int n = 0; n < 8; ++n) {
        const int o = nh * 128 + n * 16 + lw;
        const float g2 = n2g[o], b2 = n2b[o];
        #pragma unroll
        for (int m = 0; m < 2; ++m)
            #pragma unroll
            for (int rp = 0; rp < 2; ++rp) {
                const int row = mh * 32 + m * 16 + quad * 4 + 2 * rp;
                const floatx2 val = (floatx2){acc[m][n][2 * rp], acc[m][n][2 * rp + 1]};
                const floatx2 mn = (floatx2){mean[m][2 * rp], mean[m][2 * rp + 1]};
                const floatx2 rs2 = (floatx2){rsv[m][2 * rp], rsv[m][2 * rp + 1]};
                const floatx2 y2 = gelu2((val - mn) * rs2 * g2 + b2);
                ylds[row * 264 + o] = f2bf(y2[0]);
                ylds[(row + 1) * 264 + o] = f2bf(y2[1]);
            }
    }
    __syncthreads();

    // ---- epilogue: recompute residual h from x (bf16-rounded), add y ----
    {
        const int half = lane >> 5;
        const int ln32 = lane & 31;
        const int c0 = ln32 * 8;
        floatx2 w0p[4], w1p[4], pbp[4];
        #pragma unroll
        for (int j = 0; j < 4; ++j) {
            float4 wv4 = *(const float4*)(pre_w + c0 * 2 + 4 * j);
            w0p[j] = (floatx2){wv4.x, wv4.z};
            w1p[j] = (floatx2){wv4.y, wv4.w};
        }
        float pbv[8];
        *(float4*)(pbv + 0) = *(const float4*)(pre_b + c0);
        *(float4*)(pbv + 4) = *(const float4*)(pre_b + c0 + 4);
        #pragma unroll
        for (int p = 0; p < 4; ++p)
            pbp[p] = (floatx2){pbv[2 * p], pbv[2 * p + 1]};
        #pragma unroll
        for (int mm = 0; mm < 8; ++mm) {
            const int rloc = wv * 16 + mm * 2 + half;
            const int t = t0 + rloc;
            const float xa = xb0[t], xc = xb1[t];
            const uint4 yv = *(const uint4*)(&ylds[rloc * 264 + c0]);
            uint ov[4];
            const uint yw[4] = {yv.x, yv.y, yv.z, yv.w};
            #pragma unroll
            for (int p = 0; p < 4; ++p) {
                const floatx2 h2 = w0p[p] * xa + w1p[p] * xc + pbp[p];
                const float ha = bf2f(f2bf(h2[0]));
                const float hb = bf2f(f2bf(h2[1]));
                ov[p] = addbf2f(yw[p], ha, hb);
            }
            *(uint4*)(hout + hbase + (size_t)t * HC + c0) =
                make_uint4(ov[0], ov[1], ov[2], ov[3]);
        }
    }
}

// --------------------------------------------------------------- fused ----
// (R5 structure) Layers 1-2. R6: packed-f32 phase-1 / epilogue math.
__global__ __launch_bounds__(256, 3) void fused_kernel(
    const ushort* __restrict__ hin, ushort* __restrict__ hout,
    const ushort* __restrict__ wbf,
    const float* __restrict__ sep_w, const float* __restrict__ sep_b,
    const float* __restrict__ conv1_b,
    const float* __restrict__ n1g, const float* __restrict__ n1b,
    const float* __restrict__ n2g, const float* __restrict__ n2b,
    const float* __restrict__ mask, int dil)
{
    __shared__ __align__(16) ushort ylds[64 * 264];
    __shared__ float ssum[64][2];
    __shared__ float ssq[64][2];

    const int tid = threadIdx.x;
    const int lane = tid & 63;
    const int wv = tid >> 6;
    const int P = blockIdx.x;
    const int L = (P & 7) * 256 + (P >> 3);
    const int b = L >> 6;
    const int t0 = (L & 63) << 6;
    const float* maskb = mask + b * T_LEN;
    const size_t hbase = (size_t)b * T_LEN * HC;

    {
        const int half = lane >> 5;
        const int ln32 = lane & 31;
        const int c0 = ln32 * 8;
        float sw[24];
        #pragma unroll
        for (int j = 0; j < 6; ++j)
            *(float4*)(sw + 4 * j) = *(const float4*)(sep_w + c0 * 3 + 4 * j);
        float sbv[8], g1v[8], b1v[8];
        *(float4*)(sbv + 0) = *(const float4*)(sep_b + c0);
        *(float4*)(sbv + 4) = *(const float4*)(sep_b + c0 + 4);
        *(float4*)(g1v + 0) = *(const float4*)(n1g + c0);
        *(float4*)(g1v + 4) = *(const float4*)(n1g + c0 + 4);
        *(float4*)(b1v + 0) = *(const float4*)(n1b + c0);
        *(float4*)(b1v + 4) = *(const float4*)(n1b + c0 + 4);
        floatx2 sw0p[4], sw1p[4], sw2p[4], sbp[4], g1p[4], b1p[4];
        #pragma unroll
        for (int p = 0; p < 4; ++p) {
            sw0p[p] = (floatx2){sw[6 * p],     sw[6 * p + 3]};
            sw1p[p] = (floatx2){sw[6 * p + 1], sw[6 * p + 4]};
            sw2p[p] = (floatx2){sw[6 * p + 2], sw[6 * p + 5]};
            sbp[p]  = (floatx2){sbv[2 * p], sbv[2 * p + 1]};
            g1p[p]  = (floatx2){g1v[2 * p], g1v[2 * p + 1]};
            b1p[p]  = (floatx2){b1v[2 * p], b1v[2 * p + 1]};
        }

        // issue all 8 center-tap loads upfront (MLP across mm iterations)
        uint4 hraw[8];
        #pragma unroll
        for (int mm = 0; mm < 8; ++mm) {
            const int t = t0 + wv * 16 + mm * 2 + half;
            hraw[mm] = *(const uint4*)(hin + hbase + (size_t)t * HC + c0);
        }

        for (int mm = 0; mm < 8; ++mm) {
            const int rloc = wv * 16 + mm * 2 + half;
            const int t = t0 + rloc;
            uint4 rm = make_uint4(0u, 0u, 0u, 0u);
            uint4 rp4 = make_uint4(0u, 0u, 0u, 0u);
            float mkm = 0.f, mkp = 0.f;
            if (t >= dil) {
                rm = *(const uint4*)(hin + hbase + (size_t)(t - dil) * HC + c0);
                mkm = maskb[t - dil];
            }
            if (t + dil < T_LEN) {
                rp4 = *(const uint4*)(hin + hbase + (size_t)(t + dil) * HC + c0);
                mkp = maskb[t + dil];
            }
            const float mkc = maskb[t];
            const uint cw_[4] = {hraw[mm].x, hraw[mm].y, hraw[mm].z, hraw[mm].w};
            const uint mw_[4] = {rm.x, rm.y, rm.z, rm.w};
            const uint pw_[4] = {rp4.x, rp4.y, rp4.z, rp4.w};

            floatx2 v2[4];
            floatx2 s2 = (floatx2){0.f, 0.f}, q2 = (floatx2){0.f, 0.f};
            #pragma unroll
            for (int p = 0; p < 4; ++p) {
                const floatx2 hc2 = bf2x2(cw_[p]) * mkc;
                const floatx2 hm2 = bf2x2(mw_[p]) * mkm;
                const floatx2 hp2 = bf2x2(pw_[p]) * mkp;
                const floatx2 vv = sw0p[p] * hm2 + sw1p[p] * hc2
                                 + sw2p[p] * hp2 + sbp[p];
                v2[p] = vv;
                s2 += vv;
                q2 += vv * vv;
            }
            float s = s2[0] + s2[1], q = q2[0] + q2[1];
            #pragma unroll
            for (int d = 16; d > 0; d >>= 1) {
                s += __shfl_xor(s, d, 64);
                q += __shfl_xor(q, d, 64);
            }
            const float mean = s * (1.f / 256.f);
            const float var = q * (1.f / 256.f) - mean * mean;
            const float rs = rsqrtf(var + 1e-5f);
            uint pk[4];
            #pragma unroll
            for (int p = 0; p < 4; ++p) {
                const floatx2 y2 = gelu2((v2[p] - mean) * rs * g1p[p] + b1p[p]);
                pk[p] = (uint)f2bf(y2[0]) | ((uint)f2bf(y2[1]) << 16);
            }
            *(uint4*)(&ylds[rloc * 264 + c0]) = make_uint4(pk[0], pk[1], pk[2], pk[3]);
        }
    }
    __syncthreads();

    const int lw = lane & 15;
    const int quad = lane >> 4;
    const int mh = wv >> 1;
    const int nh = wv & 1;
    floatx4 acc[2][8];
    #pragma unroll
    for (int m = 0; m < 2; ++m)
        #pragma unroll
        for (int n = 0; n < 8; ++n) acc[m][n] = (floatx4){0.f, 0.f, 0.f, 0.f};

    const ushort* wb = wbf + (nh * 128 + lw) * 256 + quad * 8;
    const ushort* la0 = &ylds[(mh * 32 + lw) * 264 + quad * 8];
    const ushort* la1 = &ylds[(mh * 32 + 16 + lw) * 264 + quad * 8];

    short8 a0c = *(const short8*)(la0);
    short8 a1c = *(const short8*)(la1);
    short8 bcur[8], bnx[8];
    #pragma unroll
    for (int n = 0; n < 8; ++n)
        bcur[n] = *(const short8*)(wb + n * 4096);

    short8 a0n, a1n;
    #pragma unroll
    for (int kt = 0; kt < 8; ++kt) {
        if (kt < 7) {
            a0n = *(const short8*)(la0 + (kt + 1) * 32);
            a1n = *(const short8*)(la1 + (kt + 1) * 32);
            #pragma unroll
            for (int n = 0; n < 8; ++n)
                bnx[n] = *(const short8*)(wb + n * 4096 + (kt + 1) * 32);
        }
        #pragma unroll
        for (int n = 0; n < 8; ++n) {
            acc[0][n] = __builtin_amdgcn_mfma_f32_16x16x32_bf16(a0c, bcur[n], acc[0][n], 0, 0, 0);
            acc[1][n] = __builtin_amdgcn_mfma_f32_16x16x32_bf16(a1c, bcur[n], acc[1][n], 0, 0, 0);
        }
        a0c = a0n;
        a1c = a1n;
        #pragma unroll
        for (int n = 0; n < 8; ++n) bcur[n] = bnx[n];
    }

    uint4 hv[8];
    #pragma unroll
    for (int jj = 0; jj < 8; ++jj) {
        const int idx = jj * 256 + tid;
        const int row = idx >> 5, seg = idx & 31;
        hv[jj] = *(const uint4*)(hin + hbase + (size_t)(t0 + row) * HC + seg * 8);
    }

    floatx4 sum4[2], sq4[2];
    #pragma unroll
    for (int m = 0; m < 2; ++m) {
        sum4[m] = (floatx4){0.f, 0.f, 0.f, 0.f};
        sq4[m] = (floatx4){0.f, 0.f, 0.f, 0.f};
    }
    #pragma unroll
    for (int n = 0; n < 8; ++n) {
        const float cb = conv1_b[nh * 128 + n * 16 + lw];
        #pragma unroll
        for (int m = 0; m < 2; ++m) {
            const floatx4 val = acc[m][n] + cb;
            acc[m][n] = val;
            sum4[m] += val;
            sq4[m] += val * val;
        }
    }
    #pragma unroll
    for (int d = 1; d < 16; d <<= 1) {
        #pragma unroll
        for (int m = 0; m < 2; ++m)
            #pragma unroll
            for (int r = 0; r < 4; ++r) {
                sum4[m][r] += __shfl_xor(sum4[m][r], d, 64);
                sq4[m][r] += __shfl_xor(sq4[m][r], d, 64);
            }
    }
    if (lw == 0) {
        #pragma unroll
        for (int m = 0; m < 2; ++m)
            #pragma unroll
            for (int r = 0; r < 4; ++r) {
                ssum[mh * 32 + m * 16 + quad * 4 + r][nh] = sum4[m][r];
                ssq[mh * 32 + m * 16 + quad * 4 + r][nh] = sq4[m][r];
            }
    }
    __syncthreads();

    float mean[2][4], rsv[2][4];
    #pragma unroll
    for (int m = 0; m < 2; ++m)
        #pragma unroll
        for (int r = 0; r < 4; ++r) {
            const int row = mh * 32 + m * 16 + quad * 4 + r;
            const float s = ssum[row][0] + ssum[row][1];
            const float q = ssq[row][0] + ssq[row][1];
            mean[m][r] = s * (1.f / 256.f);
            const float var = q * (1.f / 256.f) - mean[m][r] * mean[m][r];
            rsv[m][r] = rsqrtf(var + 1e-5f);
        }
    #pragma unroll
    for (int n = 0; n < 8; ++n) {
        const int o = nh * 128 + n * 16 + lw;
        const float g2 = n2g[o], b2 = n2b[o];
        #pragma unroll
        for (int m = 0; m < 2; ++m)
            #pragma unroll
            for (int rp = 0; rp < 2; ++rp) {
                const int row = mh * 32 + m * 16 + quad * 4 + 2 * rp;
                const floatx2 val = (floatx2){acc[m][n][2 * rp], acc[m][n][2 * rp + 1]};
                const floatx2 mn = (floatx2){mean[m][2 * rp], mean[m][2 * rp + 1]};
                const floatx2 rs2 = (floatx2){rsv[m][2 * rp], rsv[m][2 * rp + 1]};
                const floatx2 y2 = gelu2((val - mn) * rs2 * g2 + b2);
                ylds[row * 264 + o] = f2bf(y2[0]);
                ylds[(row + 1) * 264 + o] = f2bf(y2[1]);
            }
    }
    __syncthreads();

    #pragma unroll
    for (int jj = 0; jj < 8; ++jj) {
        const int idx = jj * 256 + tid;
        const int row = idx >> 5, seg = idx & 31;
        const size_t g = hbase + (size_t)(t0 + row) * HC + seg * 8;
        const uint4 yv = *(const uint4*)(&ylds[row * 264 + seg * 8]);
        uint4 ov;
        ov.x = addbf2(yv.x, hv[jj].x);
        ov.y = addbf2(yv.y, hv[jj].y);
        ov.z = addbf2(yv.z, hv[jj].z);
        ov.w = addbf2(yv.w, hv[jj].w);
        *(uint4*)(hout + g) = ov;
    }
}

// ---------------------------------------------------------- fused+proj ----
// (R5 — fused layer3+proj+spline; h3 never touches global.) R6: packed math.
__global__ __launch_bounds__(256, 3) void fused_proj_kernel(
    const ushort* __restrict__ hin,
    const ushort* __restrict__ wbf, const ushort* __restrict__ pwbf,
    const float* __restrict__ sep_w, const float* __restrict__ sep_b,
    const float* __restrict__ conv1_b,
    const float* __restrict__ n1g, const float* __restrict__ n1b,
    const float* __restrict__ n2g, const float* __restrict__ n2b,
    const float* __restrict__ projb, const float* __restrict__ x,
    const float* __restrict__ mask, float* __restrict__ out, int dil)
{
    __shared__ __align__(16) ushort ylds[64 * 264];
    __shared__ float ssum[64][2];
    __shared__ float ssq[64][2];
    __shared__ float red[4];

    const int tid = threadIdx.x;
    const int lane = tid & 63;
    const int wv = tid >> 6;
    const int P = blockIdx.x;
    const int L = (P & 7) * 256 + (P >> 3);
    const int b = L >> 6;
    const int t0 = (L & 63) << 6;
    const float* maskb = mask + b * T_LEN;
    const size_t hbase = (size_t)b * T_LEN * HC;

    // ---- phase 1: dwconv(dil)+LN(n1)+gelu -> ylds ----
    {
        const int half = lane >> 5;
        const int ln32 = lane & 31;
        const int c0 = ln32 * 8;
        float sw[24];
        #pragma unroll
        for (int j = 0; j < 6; ++j)
            *(float4*)(sw + 4 * j) = *(const float4*)(sep_w + c0 * 3 + 4 * j);
        float sbv[8], g1v[8], b1v[8];
        *(float4*)(sbv + 0) = *(const float4*)(sep_b + c0);
        *(float4*)(sbv + 4) = *(const float4*)(sep_b + c0 + 4);
        *(float4*)(g1v + 0) = *(const float4*)(n1g + c0);
        *(float4*)(g1v + 4) = *(const float4*)(n1g + c0 + 4);
        *(float4*)(b1v + 0) = *(const float4*)(n1b + c0);
        *(float4*)(b1v + 4) = *(const float4*)(n1b + c0 + 4);
        floatx2 sw0p[4], sw1p[4], sw2p[4], sbp[4], g1p[4], b1p[4];
        #pragma unroll
        for (int p = 0; p < 4; ++p) {
            sw0p[p] = (floatx2){sw[6 * p],     sw[6 * p + 3]};
            sw1p[p] = (floatx2){sw[6 * p + 1], sw[6 * p + 4]};
            sw2p[p] = (floatx2){sw[6 * p + 2], sw[6 * p + 5]};
            sbp[p]  = (floatx2){sbv[2 * p], sbv[2 * p + 1]};
            g1p[p]  = (floatx2){g1v[2 * p], g1v[2 * p + 1]};
            b1p[p]  = (floatx2){b1v[2 * p], b1v[2 * p + 1]};
        }

        uint4 hraw[8];
        #pragma unroll
        for (int mm = 0; mm < 8; ++mm) {
            const int t = t0 + wv * 16 + mm * 2 + half;
            hraw[mm] = *(const uint4*)(hin + hbase + (size_t)t * HC + c0);
        }

        for (int mm = 0; mm < 8; ++mm) {
            const int rloc = wv * 16 + mm * 2 + half;
            const int t = t0 + rloc;
            uint4 rm = make_uint4(0u, 0u, 0u, 0u);
            uint4 rp4 = make_uint4(0u, 0u, 0u, 0u);
            float mkm = 0.f, mkp = 0.f;
            if (t >= dil) {
                rm = *(const uint4*)(hin + hbase + (size_t)(t - dil) * HC + c0);
                mkm = maskb[t - dil];
            }
            if (t + dil < T_LEN) {
                rp4 = *(const uint4*)(hin + hbase + (size_t)(t + dil) * HC + c0);
                mkp = maskb[t + dil];
            }
            const float mkc = maskb[t];
            const uint cw_[4] = {hraw[mm].x, hraw[mm].y, hraw[mm].z, hraw[mm].w};
            const uint mw_[4] = {rm.x, rm.y, rm.z, rm.w};
            const uint pw_[4] = {rp4.x, rp4.y, rp4.z, rp4.w};

            floatx2 v2[4];
            floatx2 s2 = (floatx2){0.f, 0.f}, q2 = (floatx2){0.f, 0.f};
            #pragma unroll
            for (int p = 0; p < 4; ++p) {
                const floatx2 hc2 = bf2x2(cw_[p]) * mkc;
                const floatx2 hm2 = bf2x2(mw_[p]) * mkm;
                const floatx2 hp2 = bf2x2(pw_[p]) * mkp;
                const floatx2 vv = sw0p[p] * hm2 + sw1p[p] * hc2
                                 + sw2p[p] * hp2 + sbp[p];
                v2[p] = vv;
                s2 += vv;
                q2 += vv * vv;
            }
            float s = s2[0] + s2[1], q = q2[0] + q2[1];
            #pragma unroll
            for (int d = 16; d > 0; d >>= 1) {
                s += __shfl_xor(s, d, 64);
                q += __shfl_xor(q, d, 64);
            }
            const float mean = s * (1.f / 256.f);
            const float var = q * (1.f / 256.f) - mean * mean;
            const float rs = rsqrtf(var + 1e-5f);
            uint pk[4];
            #pragma unroll
            for (int p = 0; p < 4; ++p) {
                const floatx2 y2 = gelu2((v2[p] - mean) * rs * g1p[p] + b1p[p]);
                pk[p] = (uint)f2bf(y2[0]) | ((uint)f2bf(y2[1]) << 16);
            }
            *(uint4*)(&ylds[rloc * 264 + c0]) = make_uint4(pk[0], pk[1], pk[2], pk[3]);
        }
    }
    __syncthreads();

    // ---- phase 2: conv1 MFMA ----
    const int lw = lane & 15;
    const int quad = lane >> 4;
    const int mh = wv >> 1;
    const int nh = wv & 1;
    floatx4 acc[2][8];
    #pragma unroll
    for (int m = 0; m < 2; ++m)
        #pragma unroll
        for (int n = 0; n < 8; ++n) acc[m][n] = (floatx4){0.f, 0.f, 0.f, 0.f};

    const ushort* wb = wbf + (nh * 128 + lw) * 256 + quad * 8;
    const ushort* la0 = &ylds[(mh * 32 + lw) * 264 + quad * 8];
    const ushort* la1 = &ylds[(mh * 32 + 16 + lw) * 264 + quad * 8];

    short8 a0c = *(const short8*)(la0);
    short8 a1c = *(const short8*)(la1);
    short8 bcur[8], bnx[8];
    #pragma unroll
    for (int n = 0; n < 8; ++n)
        bcur[n] = *(const short8*)(wb + n * 4096);

    short8 a0n, a1n;
    #pragma unroll
    for (int kt = 0; kt < 8; ++kt) {
        if (kt < 7) {
            a0n = *(const short8*)(la0 + (kt + 1) * 32);
            a1n = *(const short8*)(la1 + (kt + 1) * 32);
            #pragma unroll
            for (int n = 0; n < 8; ++n)
                bnx[n] = *(const short8*)(wb + n * 4096 + (kt + 1) * 32);
        }
        #pragma unroll
        for (int n = 0; n < 8; ++n) {
            acc[0][n] = __builtin_amdgcn_mfma_f32_16x16x32_bf16(a0c, bcur[n], acc[0][n], 0, 0, 0);
            acc[1][n] = __builtin_amdgcn_mfma_f32_16x16x32_bf16(a1c, bcur[n], acc[1][n], 0, 0, 0);
        }
        a0c = a0n;
        a1c = a1n;
        #pragma unroll
        for (int n = 0; n < 8; ++n) bcur[n] = bnx[n];
    }

    uint4 hv[8];
    #pragma unroll
    for (int jj = 0; jj < 8; ++jj) {
        const int idx = jj * 256 + tid;
        const int row = idx >> 5, seg = idx & 31;
        hv[jj] = *(const uint4*)(hin + hbase + (size_t)(t0 + row) * HC + seg * 8);
    }

    floatx4 sum4[2], sq4[2];
    #pragma unroll
    for (int m = 0; m < 2; ++m) {
        sum4[m] = (floatx4){0.f, 0.f, 0.f, 0.f};
        sq4[m] = (floatx4){0.f, 0.f, 0.f, 0.f};
    }
    #pragma unroll
    for (int n = 0; n < 8; ++n) {
        const float cb = conv1_b[nh * 128 + n * 16 + lw];
        #pragma unroll
        for (int m = 0; m < 2; ++m) {
            const floatx4 val = acc[m][n] + cb;
            acc[m][n] = val;
            sum4[m] += val;
            sq4[m] += val * val;
        }
    }
    #pragma unroll
    for (int d = 1; d < 16; d <<= 1) {
        #pragma unroll
        for (int m = 0; m < 2; ++m)
            #pragma unroll
            for (int r = 0; r < 4; ++r) {
                sum4[m][r] += __shfl_xor(sum4[m][r], d, 64);
                sq4[m][r] += __shfl_xor(sq4[m][r], d, 64);
            }
    }
    if (lw == 0) {
        #pragma unroll
        for (int m = 0; m < 2; ++m)
            #pragma unroll
            for (int r = 0; r < 4; ++r) {
                ssum[mh * 32 + m * 16 + quad * 4 + r][nh] = sum4[m][r];
                ssq[mh * 32 + m * 16 + quad * 4 + r][nh] = sq4[m][r];
            }
    }
    __syncthreads();

    float mean[2][4], rsv[2][4];
    #pragma unroll
    for (int m = 0; m < 2; ++m)
        #pragma unroll
        for (int r = 0; r < 4; ++r) {
            const int row = mh * 32 + m * 16 + quad * 4 + r;
            const float s = ssum[row][0] + ssum[row][1];
            const float q = ssq[row][0] + ssq[row][1];
            mean[m][r] = s * (1.f / 256.f);
            const float var = q * (1.f / 256.f) - mean[m][r] * mean[m][r];
            rsv[m][r] = rsqrtf(var + 1e-5f);
        }
    #pragma unroll
    for (int n = 0; n < 8; ++n) {
        const int o = nh * 128 + n * 16 + lw;
        const float g2 = n2g[o], b2 = n2b[o];
        #pragma unroll
        for (int m = 0; m < 2; ++m)
            #pragma unroll
            for (int rp = 0; rp < 2; ++rp) {
                const int row = mh * 32 + m * 16 + quad * 4 + 2 * rp;
                const floatx2 val = (floatx2){acc[m][n][2 * rp], acc[m][n][2 * rp + 1]};
                const floatx2 mn = (floatx2){mean[m][2 * rp], mean[m][2 * rp + 1]};
                const floatx2 rs2 = (floatx2){rsv[m][2 * rp], rsv[m][2 * rp + 1]};
                const floatx2 y2 = gelu2((val - mn) * rs2 * g2 + b2);
                ylds[row * 264 + o] = f2bf(y2[0]);
                ylds[(row + 1) * 264 + o] = f2bf(y2[1]);
            }
    }
    __syncthreads();

    // ---- residual add IN PLACE: ylds <- h3 = y + h (no global write) ----
    #pragma unroll
    for (int jj = 0; jj < 8; ++jj) {
        const int idx = jj * 256 + tid;
        const int row = idx >> 5, seg = idx & 31;
        uint4 yv = *(const uint4*)(&ylds[row * 264 + seg * 8]);
        uint4 ov;
        ov.x = addbf2(yv.x, hv[jj].x);
        ov.y = addbf2(yv.y, hv[jj].y);
        ov.z = addbf2(yv.z, hv[jj].z);
        ov.w = addbf2(yv.w, hv[jj].w);
        *(uint4*)(&ylds[row * 264 + seg * 8]) = ov;
    }
    __syncthreads();

    // ---- proj MFMA: A = h3 from ylds ----
    floatx4 acc2[4];
    #pragma unroll
    for (int n = 0; n < 4; ++n) acc2[n] = (floatx4){0.f, 0.f, 0.f, 0.f};
    #pragma unroll
    for (int kt = 0; kt < 8; ++kt) {
        short8 a = *(short8*)(&ylds[(wv * 16 + lw) * 264 + kt * 32 + quad * 8]);
        #pragma unroll
        for (int n = 0; n < 4; ++n) {
            short8 bb = *(const short8*)(pwbf + (n * 16 + lw) * 256 + kt * 32 + quad * 8);
            acc2[n] = __builtin_amdgcn_mfma_f32_16x16x32_bf16(a, bb, acc2[n], 0, 0, 0);
        }
    }
    __syncthreads();   // all ylds reads done -> safe to alias as slds/exch

    float* slds = reinterpret_cast<float*>(ylds);           // 64 x 65 floats
    float* exch = reinterpret_cast<float*>(ylds) + 64 * 65; // 128 x 11 floats
    #pragma unroll
    for (int n = 0; n < 4; ++n) {
        const int o = n * 16 + lw;
        const float pb = (o < 58) ? projb[o] : 0.f;
        #pragma unroll
        for (int r = 0; r < 4; ++r) {
            const int row = wv * 16 + quad * 4 + r;
            const float mv = maskb[t0 + row];
            slds[row * 65 + o] = acc2[n][r] * mv + pb;
        }
    }
    __syncthreads();

    // ---- spline (A/B pair-split) ----
    const int item = tid & 127;
    const int pos = item >> 1;
    const int ch = item & 1;
    const int t = t0 + pos;
    const bool isA = tid < 128;
    const float SC = 0.0625f;

    float cwv[11], wdv[10], chv[11], htv[10];
    float x1 = 0.f, mv = 0.f;

    if (!isA) {
        #pragma unroll
        for (int j = 1; j <= 9; ++j) {
            const float u = slds[pos * 65 + ch * 29 + 19 + j];
            exch[item * 11 + (j - 1)] = 0.001f + softplus_f(u);
        }
    } else {
        x1 = x[b * 16384 + (2 + ch) * 4096 + t];
        mv = maskb[t];
        float svA[20];
        #pragma unroll
        for (int j = 0; j < 20; ++j) svA[j] = slds[pos * 65 + ch * 29 + j];
        {
            float u[10];
            float mx = -1e30f;
            #pragma unroll
            for (int j = 0; j < 10; ++j) { u[j] = svA[j] * SC; mx = fmaxf(mx, u[j]); }
            float ssm = 0.f;
            #pragma unroll
            for (int j = 0; j < 10; ++j) { u[j] = expf(u[j] - mx); ssm += u[j]; }
            const float inv = 1.f / ssm;
            float cum = 0.f;
            cwv[0] = -5.f;
            #pragma unroll
            for (int j = 0; j < 10; ++j) {
                cum += 0.001f + 0.99f * u[j] * inv;
                cwv[j + 1] = 10.f * cum - 5.f;
            }
            cwv[10] = 5.f;
            #pragma unroll
            for (int j = 0; j < 10; ++j) wdv[j] = cwv[j + 1] - cwv[j];
        }
        {
            float u[10];
            float mx = -1e30f;
            #pragma unroll
            for (int j = 0; j < 10; ++j) { u[j] = svA[10 + j] * SC; mx = fmaxf(mx, u[j]); }
            float ssm = 0.f;
            #pragma unroll
            for (int j = 0; j < 10; ++j) { u[j] = expf(u[j] - mx); ssm += u[j]; }
            const float inv = 1.f / ssm;
            float cum = 0.f;
            chv[0] = -5.f;
            #pragma unroll
            for (int j = 0; j < 10; ++j) {
                cum += 0.001f + 0.99f * u[j] * inv;
                chv[j + 1] = 10.f * cum - 5.f;
            }
            chv[10] = 5.f;
            #pragma unroll
            for (int j = 0; j < 10; ++j) htv[j] = chv[j + 1] - chv[j];
        }
    }
    __syncthreads();   // B's exch visible to A

    float contrib = 0.f;
    if (isA) {
        float dvv[11];
        dvv[0] = 1.f;
        dvv[10] = 1.f;
        #pragma unroll
        for (int j = 1; j <= 9; ++j) dvv[j] = exch[item * 11 + (j - 1)];

        const bool inside = (x1 >= -5.f) && (x1 <= 5.f);
        const float xc = fminf(fmaxf(x1, -5.f), 5.f);
        float in_cw = cwv[0], in_w = wdv[0], in_ch = chv[0], in_h = htv[0];
        float dk = dvv[0], dk1 = dvv[1];
        #pragma unroll
        for (int j = 1; j < 10; ++j) {
            const bool ge = (xc >= cwv[j]);
            in_cw = ge ? cwv[j] : in_cw;
            in_w  = ge ? wdv[j] : in_w;
            in_ch = ge ? chv[j] : in_ch;
            in_h  = ge ? htv[j] : in_h;
            dk    = ge ? dvv[j] : dk;
            dk1   = ge ? dvv[j + 1] : dk1;
        }
        const float th = (xc - in_cw) / in_w;
        const float t1m = th * (1.f - th);
        const float dl = in_h / in_w;
        const float num = in_h * (dl * th * th + dk * t1m);
        const float den = dl + (dk + dk1 - 2.f * dl) * t1m;
        float yv = in_ch + num / den;
        const float omt = 1.f - th;
        const float dnum = dl * dl * (dk1 * th * th + 2.f * dl * t1m + dk * omt * omt);
        float lad = logf(dnum) - 2.f * logf(den);
        if (!inside) { yv = x1; lad = 0.f; }
        out[b * 16384 + (2 + ch) * 4096 + t] = yv * mv;
        contrib = lad * mv;
    }
    #pragma unroll
    for (int d = 32; d > 0; d >>= 1) contrib += __shfl_xor(contrib, d, 64);
    if (lane == 0) red[wv] = contrib;
    __syncthreads();
    if (tid == 0) atomicAdd(out + OUT_ELEMS + b, red[0] + red[1] + red[2] + red[3]);
}

// -------------------------------------------------------------- launch ----
extern "C" void kernel_launch(void* const* d_in, const int* in_sizes, int n_in,
                              void* d_out, int out_size, void* d_ws, size_t ws_size,
                              hipStream_t stream) {
    const float* x      = (const float*)d_in[0];
    const float* mask   = (const float*)d_in[1];
    const float* pre_w  = (const float*)d_in[2];
    const float* pre_b  = (const float*)d_in[3];
    const float* sep_w  = (const float*)d_in[4];
    const float* sep_b  = (const float*)d_in[5];
    const float* conv1w = (const float*)d_in[6];
    const float* conv1b = (const float*)d_in[7];
    const float* n1g    = (const float*)d_in[8];
    const float* n1b    = (const float*)d_in[9];
    const float* n2g    = (const float*)d_in[10];
    const float* n2b    = (const float*)d_in[11];
    const float* projw  = (const float*)d_in[12];
    const float* projb  = (const float*)d_in[13];
    float* out = (float*)d_out;

    ushort* h0   = (ushort*)d_ws;
    ushort* h1   = h0 + (size_t)NPOS * HC;
    ushort* wbf  = h1 + (size_t)NPOS * HC;
    ushort* pwbf = wbf + 4 * 256 * 256;

    prep_kernel<<<2113, 256, 0, stream>>>(conv1w, projw, x, mask, wbf, pwbf, out);

    // layer 0: fully fused, residual recomputed in epilogue (no hg stream)
    fused0_kernel<<<2048, 256, 0, stream>>>(x, h1, wbf,
        pre_w, pre_b, sep_w, sep_b, conv1b, n1g, n1b, n2g, n2b, mask);

    // layers 1-2: fully fused; ping-pong, never in-place
    fused_kernel<<<2048, 256, 0, stream>>>(h1, h0, wbf + 1 * 65536,
        sep_w + 1 * 768, sep_b + 1 * 256, conv1b + 1 * 256,
        n1g + 1 * 256, n1b + 1 * 256, n2g + 1 * 256, n2b + 1 * 256, mask, 3);
    fused_kernel<<<2048, 256, 0, stream>>>(h0, h1, wbf + 2 * 65536,
        sep_w + 2 * 768, sep_b + 2 * 256, conv1b + 2 * 256,
        n1g + 2 * 256, n1b + 2 * 256, n2g + 2 * 256, n2b + 2 * 256, mask, 9);

    // layer 3 + proj + spline fused: h3 never touches global memory
    fused_proj_kernel<<<2048, 256, 0, stream>>>(h1, wbf + 3 * 65536, pwbf,
        sep_w + 3 * 768, sep_b + 3 * 256, conv1b + 3 * 256,
        n1g + 3 * 256, n1b + 3 * 256, n2g + 3 * 256, n2b + 3 * 256,
        projb, x, mask, out, 27);
}